// Round 9
// baseline (20150.999 us; speedup 1.0000x reference)
//
#include <hip/hip_runtime.h>
#include <hip/hip_bf16.h>

typedef short short8 __attribute__((ext_vector_type(8)));
typedef float f32x4 __attribute__((ext_vector_type(4)));

#define BROWS 32
#define NTHR  256
#define XK    96
#define XSTR  104
#define HSTR  264
#define HIDSTR 129
#define NKT0  11
#define NKT1  16
#define NKTO  8
#define PK0_ELEMS (64*NKT0*512)
#define PK1_ELEMS (64*NKT1*512)
#define PKO_ELEMS (8*NKTO*512)

// LDS layout (bytes) — 75,408 B/block; 2 blocks/CU = 150.8KB <= 160KB
#define L_X    0
#define L_H    6656
#define HBUF   (BROWS*HSTR)          // ushort elems per H buffer (3 rotating)
#define HBUF_B (HBUF*2)              // 16896 B
#define L_HID  (L_H + 3*HBUF_B)      // 57344
#define L_OW2  (L_HID + BROWS*HIDSTR*4)  // 73856
#define L_OB2  (L_OW2 + 1536)        // 75392
#define LDS_TOTAL 75408

__device__ inline unsigned short f2bf(float x){
  unsigned u = __float_as_uint(x);
  u += 0x7FFFu + ((u >> 16) & 1u);
  return (unsigned short)(u >> 16);
}
__device__ inline float bf2f(unsigned short s){ return __uint_as_float(((unsigned)s) << 16); }
__device__ inline float sigm(float x){ return 1.f / (1.f + __expf(-x)); }
__device__ inline float ftanh(float x){ float e = __expf(2.f*x); return 1.f - 2.f/(e + 1.f); }

// ---------------- weight pre-pack: fp32 -> single bf16, MFMA B-fragment lane order ----
// layout (ushort): region base + ((ntG*NKT + kt)*64 + lane)*8 + j
// B-frag (16x16x32): lane l holds B[k=(l>>4)*8+j][n=l&15], j=0..7
// Layer-0 K-space: [0..2]=cur, [3..66]=z, [67..72]=cond, [73]=BIAS (X col 73 == 1.0),
//                  [74..95]=pad0, [96..351]=w_hh0
__global__ void pack_weights(const float* __restrict__ wih0, const float* __restrict__ whh0,
                             const float* __restrict__ bih0, const float* __restrict__ bhh0,
                             const float* __restrict__ wih1, const float* __restrict__ whh1,
                             const float* __restrict__ ow1,
                             unsigned short* __restrict__ wsb){
  int idx = blockIdx.x * blockDim.x + threadIdx.x;
  int total = PK0_ELEMS + PK1_ELEMS + PKO_ELEMS;
  if (idx >= total) return;
  float w;
  size_t off;
  if (idx < PK0_ELEMS) {
    int nt = idx / (NKT0*512), rem = idx % (NKT0*512), kt = rem / 512, li = rem % 512;
    int lane = li >> 3, j = li & 7;
    int n = lane & 15, k = ((lane >> 4) << 3) + j;
    int Kg = kt*32 + k, g = nt*16 + n;          // g = global gate-unit index [0,1024)
    if (Kg < 73)        w = wih0[g*73 + Kg];
    else if (Kg == 73)  w = bih0[g] + bhh0[g];  // bias via constant-1 input column
    else if (Kg < XK)   w = 0.f;
    else                w = whh0[g*256 + (Kg - XK)];
    off = ((size_t)(nt*NKT0 + kt)*64 + lane)*8 + j;
  } else if (idx < PK0_ELEMS + PK1_ELEMS) {
    int i2 = idx - PK0_ELEMS;
    int nt = i2 / (NKT1*512), rem = i2 % (NKT1*512), kt = rem / 512, li = rem % 512;
    int lane = li >> 3, j = li & 7;
    int n = lane & 15, k = ((lane >> 4) << 3) + j;
    int Kg = kt*32 + k, g = nt*16 + n;
    w = (Kg < 256) ? wih1[g*256 + Kg] : whh1[g*256 + (Kg - 256)];
    off = (size_t)PK0_ELEMS + ((size_t)(nt*NKT1 + kt)*64 + lane)*8 + j;
  } else {
    int i2 = idx - PK0_ELEMS - PK1_ELEMS;
    int nt = i2 / (NKTO*512), rem = i2 % (NKTO*512), kt = rem / 512, li = rem % 512;
    int lane = li >> 3, j = li & 7;
    int n = lane & 15, k = ((lane >> 4) << 3) + j;
    int Kg = kt*32 + k, uh = nt*16 + n;
    w = ow1[uh*256 + Kg];
    off = (size_t)PK0_ELEMS + (size_t)PK1_ELEMS + ((size_t)(nt*NKTO + kt)*64 + lane)*8 + j;
  }
  wsb[off] = f2bf(w);
}

// ---------------- persistent rollout kernel ----------------
// R1-R8 established: this toolchain budgets VGPRs for exactly 2 workgroups/CU
// (512thr->128 regs, 1024thr->64 regs; launch_bounds arg2 / waves_per_eu ignored).
// So: NTHR=256 -> 256 regs/wave. BROWS=32 sizes the live set to ~230 regs:
//   acc 64 (2 ut-tiles x 4 gates x 2 mt) + c-state 64 + weight ring 64 + frags/bias.
// LDS 75.4KB -> 2 blocks/CU co-resident (2 waves/SIMD from INDEPENDENT blocks:
// no shared-barrier lockstep). Zero spills -> clean L2 -> weights stay resident.
// Wave p-pass owns units u = (wv*4 + p*2 + uti)*16 + (lane&15), all 4 gates.
__global__ void __launch_bounds__(NTHR)
traj_main(const float* __restrict__ z, const float* __restrict__ cond,
          const float* __restrict__ fiw, const float* __restrict__ fib,
          const float* __restrict__ bih1, const float* __restrict__ bhh1,
          const float* __restrict__ ob1,  const float* __restrict__ ow2,
          const float* __restrict__ ob2,
          const unsigned short* __restrict__ wsb, const int* __restrict__ seqp,
          float* __restrict__ out){
  extern __shared__ char smem[];
  unsigned short* Xl  = (unsigned short*)(smem + L_X);    // [32][104] bf16: cur|z|cond|1|pad
  unsigned short* Hl  = (unsigned short*)(smem + L_H);    // 3 x [32][264] bf16 rotating
  float*          HIDl= (float*)(smem + L_HID);           // [32][129] f32
  float*          OW2l= (float*)(smem + L_OW2);           // [3][128]
  float*          OB2l= (float*)(smem + L_OB2);           // [3]

  const int tid = threadIdx.x, wv = tid >> 6, lane = tid & 63;
  const int bid = blockIdx.x;
  const int row0 = bid * BROWS;
  const int T = *seqp;

  const unsigned short* pk0i = wsb;
  const unsigned short* pk1i = wsb + (size_t)PK0_ELEMS;
  const unsigned short* pkoi = wsb + (size_t)PK0_ELEMS + (size_t)PK1_ELEMS;

  // ---- init: fill X (cur0 = cond[:3], z, cond, 1.0 bias col), copy ow2/ob2 to LDS
  {
    int r = tid >> 3, seg = tid & 7;
    int gr = row0 + r;
    for (int c = seg*13; c < seg*13 + 13; ++c) {
      float v;
      if (c < 3)        v = cond[gr*6 + c];
      else if (c < 67)  v = z[gr*64 + (c - 3)];
      else if (c < 73)  v = cond[gr*6 + (c - 67)];
      else if (c == 73) v = 1.0f;               // bias multiplier column
      else              v = 0.f;
      Xl[r*XSTR + c] = f2bf(v);
    }
  }
  if (tid < 192) { OW2l[tid] = ow2[tid]; OW2l[192 + tid] = ow2[192 + tid]; }
  if (tid < 3)   OB2l[tid] = ob2[tid];

  // ---- init h0 -> H[0], h1 -> H[1]  (fp32 VALU, one-time; 32 rows x 32 units/thread)
  {
    int r = tid >> 3, ub = (tid & 7) * 32;
    int gr = row0 + r;
    #pragma unroll 1
    for (int u = ub; u < ub + 32; ++u) {
      float s0 = fib[u], s1 = fib[256 + u];
      const float* w0r = fiw + (size_t)u * 70;
      const float* w1r = fiw + (size_t)(256 + u) * 70;
      for (int jj = 0; jj < 64; ++jj) { float xv = z[gr*64 + jj]; s0 += xv * w0r[jj]; s1 += xv * w1r[jj]; }
      for (int jj = 0; jj < 6;  ++jj) { float xv = cond[gr*6 + jj]; s0 += xv * w0r[64 + jj]; s1 += xv * w1r[64 + jj]; }
      Hl[0*HBUF + r*HSTR + u] = f2bf(s0);
      Hl[1*HBUF + r*HSTR + u] = f2bf(s1);
    }
  }

  // ---- per-lane layer-1 bias preload: [p][uti][g] (layer-0 bias folded into weights)
  float bias1r[2][2][4];
  #pragma unroll
  for (int p = 0; p < 2; ++p)
    #pragma unroll
    for (int uti = 0; uti < 2; ++uti) {
      int u = (wv*4 + p*2 + uti)*16 + (lane & 15);
      #pragma unroll
      for (int g = 0; g < 4; ++g)
        bias1r[p][uti][g] = bih1[g*256 + u] + bhh1[g*256 + u];
    }
  float ob1r[2];
  #pragma unroll
  for (int oi = 0; oi < 2; ++oi)
    ob1r[oi] = ob1[(wv*2 + oi)*16 + (lane & 15)];

  // ---- c-state in registers: index ((p*2+uti)*2+mt)*4+q, 32 per layer
  float c0s[32], c1s[32];
  #pragma unroll
  for (int i = 0; i < 32; ++i) { c0s[i] = 0.f; c1s[i] = 0.f; }

  __syncthreads();

  const int arow = lane & 15, koff = (lane >> 4) * 8;

  // rotating buffer roles: ia = h0(t), ib = h1(t), ic = free
  int ia = 0, ib = 1, ic = 2;

  for (int t = 0; t < T; ++t) {
    const unsigned short* Ha = Hl + ia*HBUF;  // h0(t)
    const unsigned short* Hb = Hl + ib*HBUF;  // h1(t)
    unsigned short*       Hc = Hl + ic*HBUF;  // free -> h0(t+1)
    unsigned short*       HaW= Hl + ia*HBUF;  // retired after B1 -> h1(t+1)

    // ===== M1: gates0 = [x|1|h0] @ W0^T (bias folded), cell 0; h0n -> H[ic] =====
    #pragma unroll
    for (int p = 0; p < 2; ++p) {
      // base for ut-tile (wv*4+p*2): tile stride NKT0*512; gate stride 16*NKT0*512
      const unsigned short* wb = pk0i + ((size_t)((wv*4 + p*2)*NKT0)*64 + lane)*8;

      // depth-1 ring: [2 slots][4 gates][2 uti]
      short8 wh[2][4][2];
      #pragma unroll
      for (int g = 0; g < 4; ++g)
        #pragma unroll
        for (int uti = 0; uti < 2; ++uti)
          wh[0][g][uti] = *(const short8*)(wb + (size_t)(g*16 + uti)*(NKT0*512));

      f32x4 acc[2][4][2];   // [uti][g][mt]
      #pragma unroll
      for (int uti = 0; uti < 2; ++uti)
        #pragma unroll
        for (int g = 0; g < 4; ++g)
          #pragma unroll
          for (int mt = 0; mt < 2; ++mt) acc[uti][g][mt] = (f32x4){0.f,0.f,0.f,0.f};

      #pragma unroll
      for (int kt = 0; kt < NKT0; ++kt) {
        const int cb = kt & 1, nb = cb ^ 1;
        if (kt + 1 < NKT0) {
          #pragma unroll
          for (int g = 0; g < 4; ++g)
            #pragma unroll
            for (int uti = 0; uti < 2; ++uti)
              wh[nb][g][uti] = *(const short8*)(wb + (size_t)(g*16 + uti)*(NKT0*512) + (size_t)(kt+1)*512);
        }
        short8 a[2];
        if (kt < 3) {
          #pragma unroll
          for (int mt = 0; mt < 2; ++mt)
            a[mt] = *(const short8*)(Xl + (mt*16 + arow)*XSTR + kt*32 + koff);
        } else {
          #pragma unroll
          for (int mt = 0; mt < 2; ++mt)
            a[mt] = *(const short8*)(Ha + (mt*16 + arow)*HSTR + (kt - 3)*32 + koff);
        }
        #pragma unroll
        for (int g = 0; g < 4; ++g)
          #pragma unroll
          for (int uti = 0; uti < 2; ++uti)
            #pragma unroll
            for (int mt = 0; mt < 2; ++mt)
              acc[uti][g][mt] = __builtin_amdgcn_mfma_f32_16x16x32_bf16(a[mt], wh[cb][g][uti], acc[uti][g][mt], 0, 0, 0);
      }

      #pragma unroll
      for (int uti = 0; uti < 2; ++uti) {
        const int u = (wv*4 + p*2 + uti)*16 + (lane & 15);
        #pragma unroll
        for (int mt = 0; mt < 2; ++mt) {
          #pragma unroll
          for (int q = 0; q < 4; ++q) {
            float iv = sigm(acc[uti][0][mt][q]);
            float fv = sigm(acc[uti][1][mt][q]);
            float gv = ftanh(acc[uti][2][mt][q]);
            float ov = sigm(acc[uti][3][mt][q]);
            int ci = ((p*2 + uti)*2 + mt)*4 + q;
            float cn = fv * c0s[ci] + iv * gv;
            c0s[ci] = cn;
            float hn = ov * ftanh(cn);
            int r = mt*16 + ((lane >> 4) << 2) + q;
            Hc[r*HSTR + u] = f2bf(hn);
          }
        }
      }
    }
    __syncthreads();  // B1: h0n complete (H[ic]); H[ia] now dead

    // ===== M2: gates1 = [h0n|h1] @ W1^T (+b), cell 1; h1n -> H[ia] (retired) =====
    #pragma unroll
    for (int p = 0; p < 2; ++p) {
      const unsigned short* wb = pk1i + ((size_t)((wv*4 + p*2)*NKT1)*64 + lane)*8;

      short8 wh[2][4][2];
      #pragma unroll
      for (int g = 0; g < 4; ++g)
        #pragma unroll
        for (int uti = 0; uti < 2; ++uti)
          wh[0][g][uti] = *(const short8*)(wb + (size_t)(g*16 + uti)*(NKT1*512));

      f32x4 acc[2][4][2];
      #pragma unroll
      for (int uti = 0; uti < 2; ++uti)
        #pragma unroll
        for (int g = 0; g < 4; ++g)
          #pragma unroll
          for (int mt = 0; mt < 2; ++mt) {
            float b = bias1r[p][uti][g];
            acc[uti][g][mt] = (f32x4){b, b, b, b};
          }

      #pragma unroll
      for (int kt = 0; kt < NKT1; ++kt) {
        const int cb = kt & 1, nb = cb ^ 1;
        if (kt + 1 < NKT1) {
          #pragma unroll
          for (int g = 0; g < 4; ++g)
            #pragma unroll
            for (int uti = 0; uti < 2; ++uti)
              wh[nb][g][uti] = *(const short8*)(wb + (size_t)(g*16 + uti)*(NKT1*512) + (size_t)(kt+1)*512);
        }
        short8 a[2];
        if (kt < 8) {
          #pragma unroll
          for (int mt = 0; mt < 2; ++mt)
            a[mt] = *(const short8*)(Hc + (mt*16 + arow)*HSTR + kt*32 + koff);
        } else {
          #pragma unroll
          for (int mt = 0; mt < 2; ++mt)
            a[mt] = *(const short8*)(Hb + (mt*16 + arow)*HSTR + (kt - 8)*32 + koff);
        }
        #pragma unroll
        for (int g = 0; g < 4; ++g)
          #pragma unroll
          for (int uti = 0; uti < 2; ++uti)
            #pragma unroll
            for (int mt = 0; mt < 2; ++mt)
              acc[uti][g][mt] = __builtin_amdgcn_mfma_f32_16x16x32_bf16(a[mt], wh[cb][g][uti], acc[uti][g][mt], 0, 0, 0);
      }

      #pragma unroll
      for (int uti = 0; uti < 2; ++uti) {
        const int u = (wv*4 + p*2 + uti)*16 + (lane & 15);
        #pragma unroll
        for (int mt = 0; mt < 2; ++mt) {
          #pragma unroll
          for (int q = 0; q < 4; ++q) {
            float iv = sigm(acc[uti][0][mt][q]);
            float fv = sigm(acc[uti][1][mt][q]);
            float gv = ftanh(acc[uti][2][mt][q]);
            float ov = sigm(acc[uti][3][mt][q]);
            int ci = ((p*2 + uti)*2 + mt)*4 + q;
            float cn = fv * c1s[ci] + iv * gv;
            c1s[ci] = cn;
            float hn = ov * ftanh(cn);
            int r = mt*16 + ((lane >> 4) << 2) + q;
            HaW[r*HSTR + u] = f2bf(hn);   // retired h0(t) buffer: safe
          }
        }
      }
    }
    __syncthreads();  // B2: h1n visible in H[ia]

    // ===== M3: hid = relu(h1n @ out_w1^T + out_b1) -> LDS fp32; 2 unit-tiles/wave =====
    {
      f32x4 acc3[2][2];   // [oi][mt]
      #pragma unroll
      for (int oi = 0; oi < 2; ++oi)
        #pragma unroll
        for (int mt = 0; mt < 2; ++mt) acc3[oi][mt] = (f32x4){ob1r[oi], ob1r[oi], ob1r[oi], ob1r[oi]};

      const unsigned short* wb = pkoi + ((size_t)((wv*2)*NKTO)*64 + lane)*8;
      short8 wh[2][2];
      #pragma unroll
      for (int oi = 0; oi < 2; ++oi)
        wh[0][oi] = *(const short8*)(wb + (size_t)oi*(NKTO*512));

      #pragma unroll
      for (int kt = 0; kt < NKTO; ++kt) {
        const int cb = kt & 1, nb = cb ^ 1;
        if (kt + 1 < NKTO) {
          #pragma unroll
          for (int oi = 0; oi < 2; ++oi)
            wh[nb][oi] = *(const short8*)(wb + (size_t)oi*(NKTO*512) + (size_t)(kt+1)*512);
        }
        short8 a[2];
        #pragma unroll
        for (int mt = 0; mt < 2; ++mt)
          a[mt] = *(const short8*)(HaW + (mt*16 + arow)*HSTR + kt*32 + koff);
        #pragma unroll
        for (int oi = 0; oi < 2; ++oi)
          #pragma unroll
          for (int mt = 0; mt < 2; ++mt)
            acc3[oi][mt] = __builtin_amdgcn_mfma_f32_16x16x32_bf16(a[mt], wh[cb][oi], acc3[oi][mt], 0, 0, 0);
      }
      #pragma unroll
      for (int oi = 0; oi < 2; ++oi) {
        const int uh = (wv*2 + oi)*16 + (lane & 15);
        #pragma unroll
        for (int mt = 0; mt < 2; ++mt)
          #pragma unroll
          for (int q = 0; q < 4; ++q) {
            float hv = fmaxf(acc3[oi][mt][q], 0.f);
            int r = mt*16 + ((lane >> 4) << 2) + q;
            HIDl[r*HIDSTR + uh] = hv;
          }
      }
    }
    __syncthreads();  // B4: hid visible

    // ===== M4: out = hid @ out_w2^T + out_b2, all 256 threads:
    // 8 threads per row, 16-wide k-partials, shfl-reduce width 8 =====
    {
      int r = tid >> 3, e = tid & 7;
      const float* hrow = HIDl + r*HIDSTR + e*16;
      float s0 = 0.f, s1 = 0.f, s2 = 0.f;
      #pragma unroll
      for (int k = 0; k < 16; ++k) {
        float hv = hrow[k];
        int kk = e*16 + k;
        s0 += hv * OW2l[kk];
        s1 += hv * OW2l[128 + kk];
        s2 += hv * OW2l[256 + kk];
      }
      #pragma unroll
      for (int d = 4; d; d >>= 1) {
        s0 += __shfl_down(s0, d, 8);
        s1 += __shfl_down(s1, d, 8);
        s2 += __shfl_down(s2, d, 8);
      }
      if (e == 0) {
        s0 += OB2l[0]; s1 += OB2l[1]; s2 += OB2l[2];
        int gr = row0 + r;
        float* orow = out + (size_t)gr * (T*3) + t*3;
        orow[0] = s0; orow[1] = s1; orow[2] = s2;
        Xl[r*XSTR + 0] = f2bf(s0);
        Xl[r*XSTR + 1] = f2bf(s1);
        Xl[r*XSTR + 2] = f2bf(s2);
      }
    }
    __syncthreads();  // B5: cur visible, hid reads done

    // rotate roles: h0(t+1) in old ic; h1(t+1) in old ia; old ib freed
    int tmp = ia; ia = ic; ic = ib; ib = tmp;
  }
}

extern "C" void kernel_launch(void* const* d_in, const int* in_sizes, int n_in,
                              void* d_out, int out_size, void* d_ws, size_t ws_size,
                              hipStream_t stream){
  const float* z    = (const float*)d_in[0];
  const float* cond = (const float*)d_in[1];
  const float* fiw  = (const float*)d_in[2];
  const float* fib  = (const float*)d_in[3];
  const float* wih0 = (const float*)d_in[4];
  const float* whh0 = (const float*)d_in[5];
  const float* bih0 = (const float*)d_in[6];
  const float* bhh0 = (const float*)d_in[7];
  const float* wih1 = (const float*)d_in[8];
  const float* whh1 = (const float*)d_in[9];
  const float* bih1 = (const float*)d_in[10];
  const float* bhh1 = (const float*)d_in[11];
  const float* ow1  = (const float*)d_in[12];
  const float* ob1  = (const float*)d_in[13];
  const float* ow2  = (const float*)d_in[14];
  const float* ob2  = (const float*)d_in[15];
  const int*   seqp = (const int*)d_in[16];
  unsigned short* wsb = (unsigned short*)d_ws;
  float* outp = (float*)d_out;

  hipFuncSetAttribute((const void*)traj_main,
                      hipFuncAttributeMaxDynamicSharedMemorySize, LDS_TOTAL);

  int packtot = PK0_ELEMS + PK1_ELEMS + PKO_ELEMS;
  pack_weights<<<(packtot + 255)/256, 256, 0, stream>>>(wih0, whh0, bih0, bhh0,
                                                        wih1, whh1, ow1, wsb);
  traj_main<<<16384/BROWS, NTHR, LDS_TOTAL, stream>>>(z, cond, fiw, fib,
                                                      bih1, bhh1,
                                                      ob1, ow2, ob2, wsb, seqp, outp);
}

// Round 10
// 9751.226 us; speedup vs baseline: 2.0665x; 2.0665x over previous
//
#include <hip/hip_runtime.h>
#include <hip/hip_bf16.h>

typedef short short8 __attribute__((ext_vector_type(8)));
typedef float f32x4 __attribute__((ext_vector_type(4)));

#define BROWS 32
#define NTHR  512
#define XK    96
#define XSTR  104
#define HSTR  264
#define BTSTR 40
#define HID2STR 136
#define NKT0  11
#define NKT1  17
#define NKTO  9
#define PK0_ELEMS (64*NKT0*512)   // 360448
#define PK1_ELEMS (64*NKT1*512)   // 557056
#define PKO_ELEMS (8*NKTO*512)    // 36864

// LDS layout (bytes) — 70,160 B/block
#define L_X    0
#define HBUF   (BROWS*HSTR)          // ushort elems per H buffer
#define HBUF_B (HBUF*2)              // 16896 B
#define L_H    6656
#define L_BT   (L_H + 3*HBUF_B)      // 57344 : [32][40] bf16 bias tile (col0=1)
#define L_HID  (L_BT + BROWS*BTSTR*2)    // 59904 : [32][136] bf16
#define L_OW2  (L_HID + BROWS*HID2STR*2) // 68608 : [3][128] f32
#define L_OB2  (L_OW2 + 1536)        // 70144
#define LDS_TOTAL 70160

__device__ inline unsigned short f2bf(float x){
  unsigned u = __float_as_uint(x);
  u += 0x7FFFu + ((u >> 16) & 1u);
  return (unsigned short)(u >> 16);
}
__device__ inline float bf2f(unsigned short s){ return __uint_as_float(((unsigned)s) << 16); }
__device__ inline float sigm(float x){ return 1.f / (1.f + __expf(-x)); }
__device__ inline float ftanh(float x){ float e = __expf(2.f*x); return 1.f - 2.f/(e + 1.f); }

// ---------------- weight pre-pack: fp32 -> bf16, MFMA B-fragment lane order ----
// layout (ushort): region base + ((ntG*NKT + kt)*64 + lane)*8 + j
// B-frag (16x16x32): lane l holds B[k=(l>>4)*8+j][n=l&15], j=0..7
// Region0 (M1): K = [0..2]cur [3..66]z [67..72]cond [73]=BIAS0 [74..95]pad [96..351]w_hh0
// Region1 (M2): K = [0..255]h0n(w_ih1) [256..511]h1(w_hh1) [512]=BIAS1 [513..543]pad
// Region2 (M3): K = [0..255]h1n(out_w1) [256]=OB1 [257..287]pad
__global__ void pack_weights(const float* __restrict__ wih0, const float* __restrict__ whh0,
                             const float* __restrict__ bih0, const float* __restrict__ bhh0,
                             const float* __restrict__ wih1, const float* __restrict__ whh1,
                             const float* __restrict__ bih1, const float* __restrict__ bhh1,
                             const float* __restrict__ ow1,  const float* __restrict__ ob1,
                             unsigned short* __restrict__ wsb){
  int idx = blockIdx.x * blockDim.x + threadIdx.x;
  int total = PK0_ELEMS + PK1_ELEMS + PKO_ELEMS;
  if (idx >= total) return;
  float w;
  size_t off;
  if (idx < PK0_ELEMS) {
    int nt = idx / (NKT0*512), rem = idx % (NKT0*512), kt = rem / 512, li = rem % 512;
    int lane = li >> 3, j = li & 7;
    int n = lane & 15, k = ((lane >> 4) << 3) + j;
    int Kg = kt*32 + k, g = nt*16 + n;
    if (Kg < 73)        w = wih0[g*73 + Kg];
    else if (Kg == 73)  w = bih0[g] + bhh0[g];
    else if (Kg < XK)   w = 0.f;
    else                w = whh0[g*256 + (Kg - XK)];
    off = ((size_t)(nt*NKT0 + kt)*64 + lane)*8 + j;
  } else if (idx < PK0_ELEMS + PK1_ELEMS) {
    int i2 = idx - PK0_ELEMS;
    int nt = i2 / (NKT1*512), rem = i2 % (NKT1*512), kt = rem / 512, li = rem % 512;
    int lane = li >> 3, j = li & 7;
    int n = lane & 15, k = ((lane >> 4) << 3) + j;
    int Kg = kt*32 + k, g = nt*16 + n;
    if (Kg < 256)       w = wih1[g*256 + Kg];
    else if (Kg < 512)  w = whh1[g*256 + (Kg - 256)];
    else if (Kg == 512) w = bih1[g] + bhh1[g];
    else                w = 0.f;
    off = (size_t)PK0_ELEMS + ((size_t)(nt*NKT1 + kt)*64 + lane)*8 + j;
  } else {
    int i2 = idx - PK0_ELEMS - PK1_ELEMS;
    int nt = i2 / (NKTO*512), rem = i2 % (NKTO*512), kt = rem / 512, li = rem % 512;
    int lane = li >> 3, j = li & 7;
    int n = lane & 15, k = ((lane >> 4) << 3) + j;
    int Kg = kt*32 + k, uh = nt*16 + n;
    if (Kg < 256)       w = ow1[uh*256 + Kg];
    else if (Kg == 256) w = ob1[uh];
    else                w = 0.f;
    off = (size_t)PK0_ELEMS + (size_t)PK1_ELEMS + ((size_t)(nt*NKTO + kt)*64 + lane)*8 + j;
  }
  wsb[off] = f2bf(w);
}

// ---------------- persistent rollout kernel ----------------
// Register budget rule (R1-R9 measured): VGPR cap = 65536/NTHR; attributes ignored.
// NTHR=512 -> 128 regs. Live classes removed wholesale to fit:
//   - no weight prefetch ring (compiler hoists with its ~16 spare regs; TLP covers rest)
//   - all biases folded into packed weights (constant-1 K-columns; BT LDS tile for M2/M3)
//   - HID stored bf16
// Demand ~= acc 32 + c 32 + frags 8 + overhead ~40 = ~112 < 128 -> no spills ->
// no scratch L2 pollution -> 1.9MB packed weights stay L2-resident.
__global__ void __launch_bounds__(NTHR)
traj_main(const float* __restrict__ z, const float* __restrict__ cond,
          const float* __restrict__ fiw, const float* __restrict__ fib,
          const float* __restrict__ ow2, const float* __restrict__ ob2,
          const unsigned short* __restrict__ wsb, const int* __restrict__ seqp,
          float* __restrict__ out){
  extern __shared__ char smem[];
  unsigned short* Xl   = (unsigned short*)(smem + L_X);    // [32][104] bf16 cur|z|cond|1|pad
  unsigned short* Hl   = (unsigned short*)(smem + L_H);    // 3 x [32][264] bf16 rotating
  unsigned short* BTl  = (unsigned short*)(smem + L_BT);   // [32][40] bf16, col0 = 1.0
  unsigned short* HIDb = (unsigned short*)(smem + L_HID);  // [32][136] bf16
  float*          OW2l = (float*)(smem + L_OW2);           // [3][128]
  float*          OB2l = (float*)(smem + L_OB2);           // [3]

  const int tid = threadIdx.x, wv = tid >> 6, lane = tid & 63;
  const int row0 = blockIdx.x * BROWS;
  const int T = *seqp;

  const unsigned short* pk0i = wsb;
  const unsigned short* pk1i = wsb + (size_t)PK0_ELEMS;
  const unsigned short* pkoi = wsb + (size_t)PK0_ELEMS + (size_t)PK1_ELEMS;

  // ---- init X: cur0=cond[:3], z, cond, 1.0 bias col (73), pad
  {
    int r = tid >> 4, seg = tid & 15;
    int gr = row0 + r;
    for (int c = seg*7; c < seg*7 + 7 && c < XSTR; ++c) {
      float v;
      if (c < 3)        v = cond[gr*6 + c];
      else if (c < 67)  v = z[gr*64 + (c - 3)];
      else if (c < 73)  v = cond[gr*6 + (c - 67)];
      else if (c == 73) v = 1.0f;
      else              v = 0.f;
      Xl[r*XSTR + c] = f2bf(v);
    }
  }
  // ---- init BT: col0 = 1.0 bf16 (0x3F80), rest 0
  for (int idx = tid; idx < BROWS*BTSTR; idx += NTHR)
    BTl[idx] = ((idx % BTSTR) == 0) ? (unsigned short)0x3F80 : (unsigned short)0;
  if (tid < 384) OW2l[tid] = ow2[tid];
  if (tid < 3)   OB2l[tid] = ob2[tid];

  // ---- init h0 -> H[0], h1 -> H[1] (fp32 VALU, one-time; 16 thr/row, 16 units each)
  {
    int r = tid >> 4, ub = (tid & 15) * 16;
    int gr = row0 + r;
    #pragma unroll 1
    for (int u = ub; u < ub + 16; ++u) {
      float s0 = fib[u], s1 = fib[256 + u];
      const float* w0r = fiw + (size_t)u * 70;
      const float* w1r = fiw + (size_t)(256 + u) * 70;
      for (int jj = 0; jj < 64; ++jj) { float xv = z[gr*64 + jj]; s0 += xv * w0r[jj]; s1 += xv * w1r[jj]; }
      for (int jj = 0; jj < 6;  ++jj) { float xv = cond[gr*6 + jj]; s0 += xv * w0r[64 + jj]; s1 += xv * w1r[64 + jj]; }
      Hl[0*HBUF + r*HSTR + u] = f2bf(s0);
      Hl[1*HBUF + r*HSTR + u] = f2bf(s1);
    }
  }

  // ---- c-state in registers: ci = (p*2+mt)*4+q, 16 per layer
  float c0s[16], c1s[16];
  #pragma unroll
  for (int i = 0; i < 16; ++i) { c0s[i] = 0.f; c1s[i] = 0.f; }

  __syncthreads();

  const int arow = lane & 15, koff = (lane >> 4) * 8;

  int ia = 0, ib = 1, ic = 2;   // ia=h0(t), ib=h1(t), ic=free

  for (int t = 0; t < T; ++t) {
    const unsigned short* Ha = Hl + ia*HBUF;
    const unsigned short* Hb = Hl + ib*HBUF;
    unsigned short*       Hc = Hl + ic*HBUF;
    unsigned short*       HaW= Hl + ia*HBUF;

    // ===== M1: gates0 (bias in X col 73); h0n -> H[ic] =====
    #pragma unroll
    for (int p = 0; p < 2; ++p) {
      const unsigned short* wb = pk0i + ((size_t)((wv*2 + p)*NKT0)*64 + lane)*8;

      f32x4 acc[2][4];
      #pragma unroll
      for (int mt = 0; mt < 2; ++mt)
        #pragma unroll
        for (int g = 0; g < 4; ++g) acc[mt][g] = (f32x4){0.f,0.f,0.f,0.f};

      #pragma unroll
      for (int kt = 0; kt < NKT0; ++kt) {
        short8 a[2];
        if (kt < 3) {
          #pragma unroll
          for (int mt = 0; mt < 2; ++mt)
            a[mt] = *(const short8*)(Xl + (mt*16 + arow)*XSTR + kt*32 + koff);
        } else {
          #pragma unroll
          for (int mt = 0; mt < 2; ++mt)
            a[mt] = *(const short8*)(Ha + (mt*16 + arow)*HSTR + (kt - 3)*32 + koff);
        }
        #pragma unroll
        for (int g = 0; g < 4; ++g) {
          const short8 bw = *(const short8*)(wb + (size_t)g*(16*NKT0*512) + (size_t)kt*512);
          #pragma unroll
          for (int mt = 0; mt < 2; ++mt)
            acc[mt][g] = __builtin_amdgcn_mfma_f32_16x16x32_bf16(a[mt], bw, acc[mt][g], 0, 0, 0);
        }
      }

      const int u = (wv*2 + p)*16 + (lane & 15);
      #pragma unroll
      for (int mt = 0; mt < 2; ++mt) {
        #pragma unroll
        for (int q = 0; q < 4; ++q) {
          float iv = sigm(acc[mt][0][q]);
          float fv = sigm(acc[mt][1][q]);
          float gv = ftanh(acc[mt][2][q]);
          float ov = sigm(acc[mt][3][q]);
          int ci = (p*2 + mt)*4 + q;
          float cn = fv * c0s[ci] + iv * gv;
          c0s[ci] = cn;
          float hn = ov * ftanh(cn);
          int r = mt*16 + ((lane >> 4) << 2) + q;
          Hc[r*HSTR + u] = f2bf(hn);
        }
      }
    }
    __syncthreads();  // B1: h0n ready; H[ia] retired

    // ===== M2: gates1 (bias via BT kt=16); h1n -> H[ia] =====
    #pragma unroll
    for (int p = 0; p < 2; ++p) {
      const unsigned short* wb = pk1i + ((size_t)((wv*2 + p)*NKT1)*64 + lane)*8;

      f32x4 acc[2][4];
      #pragma unroll
      for (int mt = 0; mt < 2; ++mt)
        #pragma unroll
        for (int g = 0; g < 4; ++g) acc[mt][g] = (f32x4){0.f,0.f,0.f,0.f};

      #pragma unroll
      for (int kt = 0; kt < NKT1; ++kt) {
        short8 a[2];
        if (kt < 8) {
          #pragma unroll
          for (int mt = 0; mt < 2; ++mt)
            a[mt] = *(const short8*)(Hc + (mt*16 + arow)*HSTR + kt*32 + koff);
        } else if (kt < 16) {
          #pragma unroll
          for (int mt = 0; mt < 2; ++mt)
            a[mt] = *(const short8*)(Hb + (mt*16 + arow)*HSTR + (kt - 8)*32 + koff);
        } else {
          #pragma unroll
          for (int mt = 0; mt < 2; ++mt)
            a[mt] = *(const short8*)(BTl + (mt*16 + arow)*BTSTR + koff);
        }
        #pragma unroll
        for (int g = 0; g < 4; ++g) {
          const short8 bw = *(const short8*)(wb + (size_t)g*(16*NKT1*512) + (size_t)kt*512);
          #pragma unroll
          for (int mt = 0; mt < 2; ++mt)
            acc[mt][g] = __builtin_amdgcn_mfma_f32_16x16x32_bf16(a[mt], bw, acc[mt][g], 0, 0, 0);
        }
      }

      const int u = (wv*2 + p)*16 + (lane & 15);
      #pragma unroll
      for (int mt = 0; mt < 2; ++mt) {
        #pragma unroll
        for (int q = 0; q < 4; ++q) {
          float iv = sigm(acc[mt][0][q]);
          float fv = sigm(acc[mt][1][q]);
          float gv = ftanh(acc[mt][2][q]);
          float ov = sigm(acc[mt][3][q]);
          int ci = (p*2 + mt)*4 + q;
          float cn = fv * c1s[ci] + iv * gv;
          c1s[ci] = cn;
          float hn = ov * ftanh(cn);
          int r = mt*16 + ((lane >> 4) << 2) + q;
          HaW[r*HSTR + u] = f2bf(hn);
        }
      }
    }
    __syncthreads();  // B2: h1n ready in H[ia]

    // ===== M3: hid = relu(h1n @ out_w1^T + b) -> HID bf16 (bias via BT kt=8) =====
    {
      const unsigned short* wb = pkoi + ((size_t)(wv*NKTO)*64 + lane)*8;
      f32x4 acc3[2];
      #pragma unroll
      for (int mt = 0; mt < 2; ++mt) acc3[mt] = (f32x4){0.f,0.f,0.f,0.f};

      #pragma unroll
      for (int kt = 0; kt < NKTO; ++kt) {
        short8 a[2];
        if (kt < 8) {
          #pragma unroll
          for (int mt = 0; mt < 2; ++mt)
            a[mt] = *(const short8*)(HaW + (mt*16 + arow)*HSTR + kt*32 + koff);
        } else {
          #pragma unroll
          for (int mt = 0; mt < 2; ++mt)
            a[mt] = *(const short8*)(BTl + (mt*16 + arow)*BTSTR + koff);
        }
        const short8 bw = *(const short8*)(wb + (size_t)kt*512);
        #pragma unroll
        for (int mt = 0; mt < 2; ++mt)
          acc3[mt] = __builtin_amdgcn_mfma_f32_16x16x32_bf16(a[mt], bw, acc3[mt], 0, 0, 0);
      }
      const int uh = wv*16 + (lane & 15);
      #pragma unroll
      for (int mt = 0; mt < 2; ++mt)
        #pragma unroll
        for (int q = 0; q < 4; ++q) {
          float hv = fmaxf(acc3[mt][q], 0.f);
          int r = mt*16 + ((lane >> 4) << 2) + q;
          HIDb[r*HID2STR + uh] = f2bf(hv);
        }
    }
    __syncthreads();  // B3: hid ready

    // ===== M4: out = hid @ out_w2^T + ob2; 16 thr/row, 8 cols each, shfl width 16 =====
    {
      int r = tid >> 4, e = tid & 15;
      const unsigned short* hrow = HIDb + r*HID2STR + e*8;
      float s0 = 0.f, s1 = 0.f, s2 = 0.f;
      #pragma unroll
      for (int k = 0; k < 8; ++k) {
        float hv = bf2f(hrow[k]);
        int kk = e*8 + k;
        s0 += hv * OW2l[kk];
        s1 += hv * OW2l[128 + kk];
        s2 += hv * OW2l[256 + kk];
      }
      #pragma unroll
      for (int d = 8; d; d >>= 1) {
        s0 += __shfl_down(s0, d, 16);
        s1 += __shfl_down(s1, d, 16);
        s2 += __shfl_down(s2, d, 16);
      }
      if (e == 0) {
        s0 += OB2l[0]; s1 += OB2l[1]; s2 += OB2l[2];
        int gr = row0 + r;
        float* orow = out + (size_t)gr * (T*3) + t*3;
        orow[0] = s0; orow[1] = s1; orow[2] = s2;
        Xl[r*XSTR + 0] = f2bf(s0);
        Xl[r*XSTR + 1] = f2bf(s1);
        Xl[r*XSTR + 2] = f2bf(s2);
      }
    }
    __syncthreads();  // B4: cur visible, hid reads done

    int tmp = ia; ia = ic; ic = ib; ib = tmp;
  }
}

extern "C" void kernel_launch(void* const* d_in, const int* in_sizes, int n_in,
                              void* d_out, int out_size, void* d_ws, size_t ws_size,
                              hipStream_t stream){
  const float* z    = (const float*)d_in[0];
  const float* cond = (const float*)d_in[1];
  const float* fiw  = (const float*)d_in[2];
  const float* fib  = (const float*)d_in[3];
  const float* wih0 = (const float*)d_in[4];
  const float* whh0 = (const float*)d_in[5];
  const float* bih0 = (const float*)d_in[6];
  const float* bhh0 = (const float*)d_in[7];
  const float* wih1 = (const float*)d_in[8];
  const float* whh1 = (const float*)d_in[9];
  const float* bih1 = (const float*)d_in[10];
  const float* bhh1 = (const float*)d_in[11];
  const float* ow1  = (const float*)d_in[12];
  const float* ob1  = (const float*)d_in[13];
  const float* ow2  = (const float*)d_in[14];
  const float* ob2  = (const float*)d_in[15];
  const int*   seqp = (const int*)d_in[16];
  unsigned short* wsb = (unsigned short*)d_ws;
  float* outp = (float*)d_out;

  hipFuncSetAttribute((const void*)traj_main,
                      hipFuncAttributeMaxDynamicSharedMemorySize, LDS_TOTAL);

  int packtot = PK0_ELEMS + PK1_ELEMS + PKO_ELEMS;
  pack_weights<<<(packtot + 255)/256, 256, 0, stream>>>(wih0, whh0, bih0, bhh0,
                                                        wih1, whh1, bih1, bhh1,
                                                        ow1, ob1, wsb);
  traj_main<<<16384/BROWS, NTHR, LDS_TOTAL, stream>>>(z, cond, fiw, fib,
                                                      ow2, ob2, wsb, seqp, outp);
}

// Round 11
// 9554.783 us; speedup vs baseline: 2.1090x; 1.0206x over previous
//
#include <hip/hip_runtime.h>
#include <hip/hip_bf16.h>

typedef short short8 __attribute__((ext_vector_type(8)));
typedef float f32x4 __attribute__((ext_vector_type(4)));

#define BROWS 32
#define NTHR  512
#define XK    96
#define XSTR  104
#define HSTR  264
#define BTSTR 40
#define HID2STR 136
#define CSTR  257
#define NKT0  11
#define NKT1  17
#define NKTO  9
#define PK0_ELEMS (64*NKT0*512)   // 360448
#define PK1_ELEMS (64*NKT1*512)   // 557056
#define PKO_ELEMS (8*NKTO*512)    // 36864

// LDS layout (bytes) — 135,952 B/block
#define L_X    0
#define HBUF   (BROWS*HSTR)              // ushort elems per H buffer
#define HBUF_B (HBUF*2)                  // 16896 B
#define L_H    6656
#define L_BT   (L_H + 3*HBUF_B)          // 57344 : [32][40] bf16 bias tile (col0=1)
#define L_HID  (L_BT + BROWS*BTSTR*2)    // 59904 : [32][136] bf16
#define L_OW2  (L_HID + BROWS*HID2STR*2) // 68608 : [3][128] f32
#define L_OB2  (L_OW2 + 1536)            // 70144
#define L_C0   (L_OB2 + 16)              // 70160 : [32][257] f32 (lane-private c, layer0)
#define L_C1   (L_C0 + BROWS*CSTR*4)     // 103056: [32][257] f32 (layer1)
#define LDS_TOTAL (L_C1 + BROWS*CSTR*4)  // 135952

__device__ inline unsigned short f2bf(float x){
  unsigned u = __float_as_uint(x);
  u += 0x7FFFu + ((u >> 16) & 1u);
  return (unsigned short)(u >> 16);
}
__device__ inline float bf2f(unsigned short s){ return __uint_as_float(((unsigned)s) << 16); }
__device__ inline float sigm(float x){ return 1.f / (1.f + __expf(-x)); }
__device__ inline float ftanh(float x){ float e = __expf(2.f*x); return 1.f - 2.f/(e + 1.f); }

// ---------------- weight pre-pack: fp32 -> bf16, MFMA B-fragment lane order ----
// layout (ushort): region base + ((ntG*NKT + kt)*64 + lane)*8 + j
// B-frag (16x16x32): lane l holds B[k=(l>>4)*8+j][n=l&15], j=0..7
// Region0 (M1): K = [0..2]cur [3..66]z [67..72]cond [73]=BIAS0 [74..95]pad [96..351]w_hh0
// Region1 (M2): K = [0..255]h0n(w_ih1) [256..511]h1(w_hh1) [512]=BIAS1 [513..543]pad
// Region2 (M3): K = [0..255]h1n(out_w1) [256]=OB1 [257..287]pad
__global__ void pack_weights(const float* __restrict__ wih0, const float* __restrict__ whh0,
                             const float* __restrict__ bih0, const float* __restrict__ bhh0,
                             const float* __restrict__ wih1, const float* __restrict__ whh1,
                             const float* __restrict__ bih1, const float* __restrict__ bhh1,
                             const float* __restrict__ ow1,  const float* __restrict__ ob1,
                             unsigned short* __restrict__ wsb){
  int idx = blockIdx.x * blockDim.x + threadIdx.x;
  int total = PK0_ELEMS + PK1_ELEMS + PKO_ELEMS;
  if (idx >= total) return;
  float w;
  size_t off;
  if (idx < PK0_ELEMS) {
    int nt = idx / (NKT0*512), rem = idx % (NKT0*512), kt = rem / 512, li = rem % 512;
    int lane = li >> 3, j = li & 7;
    int n = lane & 15, k = ((lane >> 4) << 3) + j;
    int Kg = kt*32 + k, g = nt*16 + n;
    if (Kg < 73)        w = wih0[g*73 + Kg];
    else if (Kg == 73)  w = bih0[g] + bhh0[g];
    else if (Kg < XK)   w = 0.f;
    else                w = whh0[g*256 + (Kg - XK)];
    off = ((size_t)(nt*NKT0 + kt)*64 + lane)*8 + j;
  } else if (idx < PK0_ELEMS + PK1_ELEMS) {
    int i2 = idx - PK0_ELEMS;
    int nt = i2 / (NKT1*512), rem = i2 % (NKT1*512), kt = rem / 512, li = rem % 512;
    int lane = li >> 3, j = li & 7;
    int n = lane & 15, k = ((lane >> 4) << 3) + j;
    int Kg = kt*32 + k, g = nt*16 + n;
    if (Kg < 256)       w = wih1[g*256 + Kg];
    else if (Kg < 512)  w = whh1[g*256 + (Kg - 256)];
    else if (Kg == 512) w = bih1[g] + bhh1[g];
    else                w = 0.f;
    off = (size_t)PK0_ELEMS + ((size_t)(nt*NKT1 + kt)*64 + lane)*8 + j;
  } else {
    int i2 = idx - PK0_ELEMS - PK1_ELEMS;
    int nt = i2 / (NKTO*512), rem = i2 % (NKTO*512), kt = rem / 512, li = rem % 512;
    int lane = li >> 3, j = li & 7;
    int n = lane & 15, k = ((lane >> 4) << 3) + j;
    int Kg = kt*32 + k, uh = nt*16 + n;
    if (Kg < 256)       w = ow1[uh*256 + Kg];
    else if (Kg == 256) w = ob1[uh];
    else                w = 0.f;
    off = (size_t)PK0_ELEMS + (size_t)PK1_ELEMS + ((size_t)(nt*NKTO + kt)*64 + lane)*8 + j;
  }
  wsb[off] = f2bf(w);
}

// ---------------- persistent rollout kernel ----------------
// R1-R10 chain: VGPR cap = 65536/NTHR (hard); my live estimates run ~40 under the
// compiler's (it hoists weight loads to the cap, evicting long-lived c-state);
// c spills -> ~8MB/XCD hot scratch -> L2 thrash -> ~50% weight miss -> L3 latency-bound.
// Fix: c-state lives in LDS f32 (lane-private: same lane writes & reads its own
// (row,unit) cells -> no barriers needed, CSTR=257 avoids bank aliasing).
// Register demand ~80 << 128: hoisting now fills spare regs instead of spilling.
__global__ void __launch_bounds__(NTHR)
traj_main(const float* __restrict__ z, const float* __restrict__ cond,
          const float* __restrict__ fiw, const float* __restrict__ fib,
          const float* __restrict__ ow2, const float* __restrict__ ob2,
          const unsigned short* __restrict__ wsb, const int* __restrict__ seqp,
          float* __restrict__ out){
  extern __shared__ char smem[];
  unsigned short* Xl   = (unsigned short*)(smem + L_X);    // [32][104] bf16 cur|z|cond|1|pad
  unsigned short* Hl   = (unsigned short*)(smem + L_H);    // 3 x [32][264] bf16 rotating
  unsigned short* BTl  = (unsigned short*)(smem + L_BT);   // [32][40] bf16, col0 = 1.0
  unsigned short* HIDb = (unsigned short*)(smem + L_HID);  // [32][136] bf16
  float*          OW2l = (float*)(smem + L_OW2);           // [3][128]
  float*          OB2l = (float*)(smem + L_OB2);           // [3]
  float*          C0l  = (float*)(smem + L_C0);            // [32][257] f32
  float*          C1l  = (float*)(smem + L_C1);            // [32][257] f32

  const int tid = threadIdx.x, wv = tid >> 6, lane = tid & 63;
  const int row0 = blockIdx.x * BROWS;
  const int T = *seqp;

  const unsigned short* pk0i = wsb;
  const unsigned short* pk1i = wsb + (size_t)PK0_ELEMS;
  const unsigned short* pkoi = wsb + (size_t)PK0_ELEMS + (size_t)PK1_ELEMS;

  // ---- init X: cur0=cond[:3], z, cond, 1.0 bias col (73), pad
  {
    int r = tid >> 4, seg = tid & 15;
    int gr = row0 + r;
    for (int c = seg*7; c < seg*7 + 7 && c < XSTR; ++c) {
      float v;
      if (c < 3)        v = cond[gr*6 + c];
      else if (c < 67)  v = z[gr*64 + (c - 3)];
      else if (c < 73)  v = cond[gr*6 + (c - 67)];
      else if (c == 73) v = 1.0f;
      else              v = 0.f;
      Xl[r*XSTR + c] = f2bf(v);
    }
  }
  // ---- init BT: col0 = 1.0 bf16, rest 0; zero c-state
  for (int idx = tid; idx < BROWS*BTSTR; idx += NTHR)
    BTl[idx] = ((idx % BTSTR) == 0) ? (unsigned short)0x3F80 : (unsigned short)0;
  for (int idx = tid; idx < BROWS*CSTR; idx += NTHR) { C0l[idx] = 0.f; C1l[idx] = 0.f; }
  if (tid < 384) OW2l[tid] = ow2[tid];
  if (tid < 3)   OB2l[tid] = ob2[tid];

  // ---- init h0 -> H[0], h1 -> H[1] (fp32 VALU, one-time; 16 thr/row, 16 units each)
  {
    int r = tid >> 4, ub = (tid & 15) * 16;
    int gr = row0 + r;
    #pragma unroll 1
    for (int u = ub; u < ub + 16; ++u) {
      float s0 = fib[u], s1 = fib[256 + u];
      const float* w0r = fiw + (size_t)u * 70;
      const float* w1r = fiw + (size_t)(256 + u) * 70;
      for (int jj = 0; jj < 64; ++jj) { float xv = z[gr*64 + jj]; s0 += xv * w0r[jj]; s1 += xv * w1r[jj]; }
      for (int jj = 0; jj < 6;  ++jj) { float xv = cond[gr*6 + jj]; s0 += xv * w0r[64 + jj]; s1 += xv * w1r[64 + jj]; }
      Hl[0*HBUF + r*HSTR + u] = f2bf(s0);
      Hl[1*HBUF + r*HSTR + u] = f2bf(s1);
    }
  }

  __syncthreads();

  const int arow = lane & 15, koff = (lane >> 4) * 8;

  int ia = 0, ib = 1, ic = 2;   // ia=h0(t), ib=h1(t), ic=free

  for (int t = 0; t < T; ++t) {
    const unsigned short* Ha = Hl + ia*HBUF;
    const unsigned short* Hb = Hl + ib*HBUF;
    unsigned short*       Hc = Hl + ic*HBUF;
    unsigned short*       HaW= Hl + ia*HBUF;

    // ===== M1: gates0 (bias in X col 73); h0n -> H[ic]; c0 in LDS =====
    #pragma unroll
    for (int p = 0; p < 2; ++p) {
      const unsigned short* wb = pk0i + ((size_t)((wv*2 + p)*NKT0)*64 + lane)*8;

      f32x4 acc[2][4];
      #pragma unroll
      for (int mt = 0; mt < 2; ++mt)
        #pragma unroll
        for (int g = 0; g < 4; ++g) acc[mt][g] = (f32x4){0.f,0.f,0.f,0.f};

      #pragma unroll
      for (int kt = 0; kt < NKT0; ++kt) {
        short8 a[2];
        if (kt < 3) {
          #pragma unroll
          for (int mt = 0; mt < 2; ++mt)
            a[mt] = *(const short8*)(Xl + (mt*16 + arow)*XSTR + kt*32 + koff);
        } else {
          #pragma unroll
          for (int mt = 0; mt < 2; ++mt)
            a[mt] = *(const short8*)(Ha + (mt*16 + arow)*HSTR + (kt - 3)*32 + koff);
        }
        #pragma unroll
        for (int g = 0; g < 4; ++g) {
          const short8 bw = *(const short8*)(wb + (size_t)g*(16*NKT0*512) + (size_t)kt*512);
          #pragma unroll
          for (int mt = 0; mt < 2; ++mt)
            acc[mt][g] = __builtin_amdgcn_mfma_f32_16x16x32_bf16(a[mt], bw, acc[mt][g], 0, 0, 0);
        }
      }

      const int u = (wv*2 + p)*16 + (lane & 15);
      #pragma unroll
      for (int mt = 0; mt < 2; ++mt) {
        #pragma unroll
        for (int q = 0; q < 4; ++q) {
          float iv = sigm(acc[mt][0][q]);
          float fv = sigm(acc[mt][1][q]);
          float gv = ftanh(acc[mt][2][q]);
          float ov = sigm(acc[mt][3][q]);
          int r = mt*16 + ((lane >> 4) << 2) + q;
          float cn = fv * C0l[r*CSTR + u] + iv * gv;
          C0l[r*CSTR + u] = cn;
          float hn = ov * ftanh(cn);
          Hc[r*HSTR + u] = f2bf(hn);
        }
      }
    }
    __syncthreads();  // B1: h0n ready; H[ia] retired

    // ===== M2: gates1 (bias via BT kt=16); h1n -> H[ia]; c1 in LDS =====
    #pragma unroll
    for (int p = 0; p < 2; ++p) {
      const unsigned short* wb = pk1i + ((size_t)((wv*2 + p)*NKT1)*64 + lane)*8;

      f32x4 acc[2][4];
      #pragma unroll
      for (int mt = 0; mt < 2; ++mt)
        #pragma unroll
        for (int g = 0; g < 4; ++g) acc[mt][g] = (f32x4){0.f,0.f,0.f,0.f};

      #pragma unroll
      for (int kt = 0; kt < NKT1; ++kt) {
        short8 a[2];
        if (kt < 8) {
          #pragma unroll
          for (int mt = 0; mt < 2; ++mt)
            a[mt] = *(const short8*)(Hc + (mt*16 + arow)*HSTR + kt*32 + koff);
        } else if (kt < 16) {
          #pragma unroll
          for (int mt = 0; mt < 2; ++mt)
            a[mt] = *(const short8*)(Hb + (mt*16 + arow)*HSTR + (kt - 8)*32 + koff);
        } else {
          #pragma unroll
          for (int mt = 0; mt < 2; ++mt)
            a[mt] = *(const short8*)(BTl + (mt*16 + arow)*BTSTR + koff);
        }
        #pragma unroll
        for (int g = 0; g < 4; ++g) {
          const short8 bw = *(const short8*)(wb + (size_t)g*(16*NKT1*512) + (size_t)kt*512);
          #pragma unroll
          for (int mt = 0; mt < 2; ++mt)
            acc[mt][g] = __builtin_amdgcn_mfma_f32_16x16x32_bf16(a[mt], bw, acc[mt][g], 0, 0, 0);
        }
      }

      const int u = (wv*2 + p)*16 + (lane & 15);
      #pragma unroll
      for (int mt = 0; mt < 2; ++mt) {
        #pragma unroll
        for (int q = 0; q < 4; ++q) {
          float iv = sigm(acc[mt][0][q]);
          float fv = sigm(acc[mt][1][q]);
          float gv = ftanh(acc[mt][2][q]);
          float ov = sigm(acc[mt][3][q]);
          int r = mt*16 + ((lane >> 4) << 2) + q;
          float cn = fv * C1l[r*CSTR + u] + iv * gv;
          C1l[r*CSTR + u] = cn;
          float hn = ov * ftanh(cn);
          HaW[r*HSTR + u] = f2bf(hn);
        }
      }
    }
    __syncthreads();  // B2: h1n ready in H[ia]

    // ===== M3: hid = relu(h1n @ out_w1^T + b) -> HID bf16 (bias via BT kt=8) =====
    {
      const unsigned short* wb = pkoi + ((size_t)(wv*NKTO)*64 + lane)*8;
      f32x4 acc3[2];
      #pragma unroll
      for (int mt = 0; mt < 2; ++mt) acc3[mt] = (f32x4){0.f,0.f,0.f,0.f};

      #pragma unroll
      for (int kt = 0; kt < NKTO; ++kt) {
        short8 a[2];
        if (kt < 8) {
          #pragma unroll
          for (int mt = 0; mt < 2; ++mt)
            a[mt] = *(const short8*)(HaW + (mt*16 + arow)*HSTR + kt*32 + koff);
        } else {
          #pragma unroll
          for (int mt = 0; mt < 2; ++mt)
            a[mt] = *(const short8*)(BTl + (mt*16 + arow)*BTSTR + koff);
        }
        const short8 bw = *(const short8*)(wb + (size_t)kt*512);
        #pragma unroll
        for (int mt = 0; mt < 2; ++mt)
          acc3[mt] = __builtin_amdgcn_mfma_f32_16x16x32_bf16(a[mt], bw, acc3[mt], 0, 0, 0);
      }
      const int uh = wv*16 + (lane & 15);
      #pragma unroll
      for (int mt = 0; mt < 2; ++mt)
        #pragma unroll
        for (int q = 0; q < 4; ++q) {
          float hv = fmaxf(acc3[mt][q], 0.f);
          int r = mt*16 + ((lane >> 4) << 2) + q;
          HIDb[r*HID2STR + uh] = f2bf(hv);
        }
    }
    __syncthreads();  // B3: hid ready

    // ===== M4: out = hid @ out_w2^T + ob2; 16 thr/row, 8 cols each, shfl width 16 =====
    {
      int r = tid >> 4, e = tid & 15;
      const unsigned short* hrow = HIDb + r*HID2STR + e*8;
      float s0 = 0.f, s1 = 0.f, s2 = 0.f;
      #pragma unroll
      for (int k = 0; k < 8; ++k) {
        float hv = bf2f(hrow[k]);
        int kk = e*8 + k;
        s0 += hv * OW2l[kk];
        s1 += hv * OW2l[128 + kk];
        s2 += hv * OW2l[256 + kk];
      }
      #pragma unroll
      for (int d = 8; d; d >>= 1) {
        s0 += __shfl_down(s0, d, 16);
        s1 += __shfl_down(s1, d, 16);
        s2 += __shfl_down(s2, d, 16);
      }
      if (e == 0) {
        s0 += OB2l[0]; s1 += OB2l[1]; s2 += OB2l[2];
        int gr = row0 + r;
        float* orow = out + (size_t)gr * (T*3) + t*3;
        orow[0] = s0; orow[1] = s1; orow[2] = s2;
        Xl[r*XSTR + 0] = f2bf(s0);
        Xl[r*XSTR + 1] = f2bf(s1);
        Xl[r*XSTR + 2] = f2bf(s2);
      }
    }
    __syncthreads();  // B4: cur visible, hid reads done

    int tmp = ia; ia = ic; ic = ib; ib = tmp;
  }
}

extern "C" void kernel_launch(void* const* d_in, const int* in_sizes, int n_in,
                              void* d_out, int out_size, void* d_ws, size_t ws_size,
                              hipStream_t stream){
  const float* z    = (const float*)d_in[0];
  const float* cond = (const float*)d_in[1];
  const float* fiw  = (const float*)d_in[2];
  const float* fib  = (const float*)d_in[3];
  const float* wih0 = (const float*)d_in[4];
  const float* whh0 = (const float*)d_in[5];
  const float* bih0 = (const float*)d_in[6];
  const float* bhh0 = (const float*)d_in[7];
  const float* wih1 = (const float*)d_in[8];
  const float* whh1 = (const float*)d_in[9];
  const float* bih1 = (const float*)d_in[10];
  const float* bhh1 = (const float*)d_in[11];
  const float* ow1  = (const float*)d_in[12];
  const float* ob1  = (const float*)d_in[13];
  const float* ow2  = (const float*)d_in[14];
  const float* ob2  = (const float*)d_in[15];
  const int*   seqp = (const int*)d_in[16];
  unsigned short* wsb = (unsigned short*)d_ws;
  float* outp = (float*)d_out;

  hipFuncSetAttribute((const void*)traj_main,
                      hipFuncAttributeMaxDynamicSharedMemorySize, LDS_TOTAL);

  int packtot = PK0_ELEMS + PK1_ELEMS + PKO_ELEMS;
  pack_weights<<<(packtot + 255)/256, 256, 0, stream>>>(wih0, whh0, bih0, bhh0,
                                                        wih1, whh1, bih1, bhh1,
                                                        ow1, ob1, wsb);
  traj_main<<<16384/BROWS, NTHR, LDS_TOTAL, stream>>>(z, cond, fiw, fib,
                                                      ow2, ob2, wsb, seqp, outp);
}

// Round 12
// 9070.766 us; speedup vs baseline: 2.2215x; 1.0534x over previous
//
#include <hip/hip_runtime.h>
#include <hip/hip_bf16.h>

typedef short short8 __attribute__((ext_vector_type(8)));
typedef float f32x4 __attribute__((ext_vector_type(4)));

#define BROWS 32
#define NTHR  512
#define XK    96
#define XSTR  104
#define HSTR  264
#define BTSTR 40
#define HID2STR 136
#define NKT0  11
#define NKT1  17
#define NKTO  9
#define PK0_ELEMS (64*NKT0*512)   // 360448
#define PK1_ELEMS (64*NKT1*512)   // 557056
#define PKO_ELEMS (8*NKTO*512)    // 36864

// LDS layout (bytes)
#define L_X    0
#define HBUF   (BROWS*HSTR)              // ushort elems per H buffer
#define HBUF_B (HBUF*2)                  // 16896 B
#define L_H    6656
#define L_BT   (L_H + 3*HBUF_B)          // 57344 : [32][40] bf16 bias tile (col0=1)
#define L_OW2  (L_BT + BROWS*BTSTR*2)    // 59904 : [3][128] f32
#define L_OB2  (L_OW2 + 1536)            // 61440
#define L_RING 62464                     // 8 waves x 12 slots x 1KB
#define LDS_TOTAL (L_RING + 8*12*1024)   // 160768 (<= 163840)
// HID ([32][136] bf16, 8704B) overlays the DEAD H buffer (old h1) during M3/M4.

#define WAITVM(N) { int _n=(N); \
  if(_n<=0)      asm volatile("s_waitcnt vmcnt(0)":::"memory"); \
  else if(_n==1) asm volatile("s_waitcnt vmcnt(1)":::"memory"); \
  else if(_n==2) asm volatile("s_waitcnt vmcnt(2)":::"memory"); \
  else if(_n==3) asm volatile("s_waitcnt vmcnt(3)":::"memory"); \
  else if(_n==4) asm volatile("s_waitcnt vmcnt(4)":::"memory"); \
  else if(_n==5) asm volatile("s_waitcnt vmcnt(5)":::"memory"); \
  else if(_n==6) asm volatile("s_waitcnt vmcnt(6)":::"memory"); \
  else           asm volatile("s_waitcnt vmcnt(7)":::"memory"); }
#define LGKM6 asm volatile("s_waitcnt lgkmcnt(6)":::"memory")
#define LGKM0 asm volatile("s_waitcnt lgkmcnt(0)":::"memory")

__device__ inline unsigned short f2bf(float x){
  unsigned u = __float_as_uint(x);
  u += 0x7FFFu + ((u >> 16) & 1u);
  return (unsigned short)(u >> 16);
}
__device__ inline float bf2f(unsigned short s){ return __uint_as_float(((unsigned)s) << 16); }
__device__ inline float sigm(float x){ return 1.f / (1.f + __expf(-x)); }
__device__ inline float ftanh(float x){ float e = __expf(2.f*x); return 1.f - 2.f/(e + 1.f); }

// one 1KB weight tile: per-lane global src (base+lane*16B), wave-uniform LDS dst.
// HW writes LDS at dst + lane*16 -> exactly the consumption layout. Zero VGPR cost.
__device__ __forceinline__ void stage16(const unsigned short* g, unsigned short* l){
  __builtin_amdgcn_global_load_lds(
      (const __attribute__((address_space(1))) unsigned int*)g,
      (__attribute__((address_space(3))) unsigned int*)l, 16, 0, 0);
}

// ---------------- weight pre-pack: fp32 -> bf16, MFMA B-fragment lane order ----
// layout (ushort): region base + ((ntG*NKT + kt)*64 + lane)*8 + j
// Region0 (M1): K = [0..2]cur [3..66]z [67..72]cond [73]=BIAS0 [74..95]pad [96..351]w_hh0
// Region1 (M2): K = [0..255]h0n(w_ih1) [256..511]h1(w_hh1) [512]=BIAS1 [513..543]pad
// Region2 (M3): K = [0..255]h1n(out_w1) [256]=OB1 [257..287]pad
__global__ void pack_weights(const float* __restrict__ wih0, const float* __restrict__ whh0,
                             const float* __restrict__ bih0, const float* __restrict__ bhh0,
                             const float* __restrict__ wih1, const float* __restrict__ whh1,
                             const float* __restrict__ bih1, const float* __restrict__ bhh1,
                             const float* __restrict__ ow1,  const float* __restrict__ ob1,
                             unsigned short* __restrict__ wsb){
  int idx = blockIdx.x * blockDim.x + threadIdx.x;
  int total = PK0_ELEMS + PK1_ELEMS + PKO_ELEMS;
  if (idx >= total) return;
  float w;
  size_t off;
  if (idx < PK0_ELEMS) {
    int nt = idx / (NKT0*512), rem = idx % (NKT0*512), kt = rem / 512, li = rem % 512;
    int lane = li >> 3, j = li & 7;
    int n = lane & 15, k = ((lane >> 4) << 3) + j;
    int Kg = kt*32 + k, g = nt*16 + n;
    if (Kg < 73)        w = wih0[g*73 + Kg];
    else if (Kg == 73)  w = bih0[g] + bhh0[g];
    else if (Kg < XK)   w = 0.f;
    else                w = whh0[g*256 + (Kg - XK)];
    off = ((size_t)(nt*NKT0 + kt)*64 + lane)*8 + j;
  } else if (idx < PK0_ELEMS + PK1_ELEMS) {
    int i2 = idx - PK0_ELEMS;
    int nt = i2 / (NKT1*512), rem = i2 % (NKT1*512), kt = rem / 512, li = rem % 512;
    int lane = li >> 3, j = li & 7;
    int n = lane & 15, k = ((lane >> 4) << 3) + j;
    int Kg = kt*32 + k, g = nt*16 + n;
    if (Kg < 256)       w = wih1[g*256 + Kg];
    else if (Kg < 512)  w = whh1[g*256 + (Kg - 256)];
    else if (Kg == 512) w = bih1[g] + bhh1[g];
    else                w = 0.f;
    off = (size_t)PK0_ELEMS + ((size_t)(nt*NKT1 + kt)*64 + lane)*8 + j;
  } else {
    int i2 = idx - PK0_ELEMS - PK1_ELEMS;
    int nt = i2 / (NKTO*512), rem = i2 % (NKTO*512), kt = rem / 512, li = rem % 512;
    int lane = li >> 3, j = li & 7;
    int n = lane & 15, k = ((lane >> 4) << 3) + j;
    int Kg = kt*32 + k, uh = nt*16 + n;
    if (Kg < 256)       w = ow1[uh*256 + Kg];
    else if (Kg == 256) w = ob1[uh];
    else                w = 0.f;
    off = (size_t)PK0_ELEMS + (size_t)PK1_ELEMS + ((size_t)(nt*NKTO + kt)*64 + lane)*8 + j;
  }
  wsb[off] = f2bf(w);
}

// ---------------- persistent rollout kernel ----------------
// R1-R11: VGPR-streamed weights force the allocator to the 128 cap -> per-step spills
// -> L2 scratch pollution -> ~55% weight hit -> latency-bound at 7-12% MfmaUtil.
// Fix: weights stream HBM/L2 -> LDS via global_load_lds (zero VGPR), per-wave private
// 12-slot ring, counted vmcnt(4) depth-8 pipeline (never drained mid-pass), lgkmcnt(6)
// slot-reuse guard. Register demand ~100 < 128 -> nothing to spill.
__global__ void __launch_bounds__(NTHR)
traj_main(const float* __restrict__ z, const float* __restrict__ cond,
          const float* __restrict__ fiw, const float* __restrict__ fib,
          const float* __restrict__ ow2, const float* __restrict__ ob2,
          const unsigned short* __restrict__ wsb, const int* __restrict__ seqp,
          float* __restrict__ out){
  extern __shared__ char smem[];
  unsigned short* Xl   = (unsigned short*)(smem + L_X);    // [32][104] bf16
  unsigned short* Hl   = (unsigned short*)(smem + L_H);    // 3 x [32][264] bf16 rotating
  unsigned short* BTl  = (unsigned short*)(smem + L_BT);   // [32][40] bf16, col0 = 1.0
  float*          OW2l = (float*)(smem + L_OW2);           // [3][128]
  float*          OB2l = (float*)(smem + L_OB2);           // [3]

  const int tid = threadIdx.x, wv = tid >> 6, lane = tid & 63;
  const int row0 = blockIdx.x * BROWS;
  const int T = *seqp;

  const unsigned short* pk0i = wsb;
  const unsigned short* pk1i = wsb + (size_t)PK0_ELEMS;
  const unsigned short* pkoi = wsb + (size_t)PK0_ELEMS + (size_t)PK1_ELEMS;
  unsigned short* RG = (unsigned short*)(smem + L_RING) + (size_t)wv*(12*512);

  // ---- init X: cur0=cond[:3], z, cond, 1.0 bias col (73), pad
  {
    int r = tid >> 4, seg = tid & 15;
    int gr = row0 + r;
    for (int c = seg*7; c < seg*7 + 7 && c < XSTR; ++c) {
      float v;
      if (c < 3)        v = cond[gr*6 + c];
      else if (c < 67)  v = z[gr*64 + (c - 3)];
      else if (c < 73)  v = cond[gr*6 + (c - 67)];
      else if (c == 73) v = 1.0f;
      else              v = 0.f;
      Xl[r*XSTR + c] = f2bf(v);
    }
  }
  for (int idx = tid; idx < BROWS*BTSTR; idx += NTHR)
    BTl[idx] = ((idx % BTSTR) == 0) ? (unsigned short)0x3F80 : (unsigned short)0;
  if (tid < 384) OW2l[tid] = ow2[tid];
  if (tid < 3)   OB2l[tid] = ob2[tid];

  // ---- init h0 -> H[0], h1 -> H[1]
  {
    int r = tid >> 4, ub = (tid & 15) * 16;
    int gr = row0 + r;
    #pragma unroll 1
    for (int u = ub; u < ub + 16; ++u) {
      float s0 = fib[u], s1 = fib[256 + u];
      const float* w0r = fiw + (size_t)u * 70;
      const float* w1r = fiw + (size_t)(256 + u) * 70;
      for (int jj = 0; jj < 64; ++jj) { float xv = z[gr*64 + jj]; s0 += xv * w0r[jj]; s1 += xv * w1r[jj]; }
      for (int jj = 0; jj < 6;  ++jj) { float xv = cond[gr*6 + jj]; s0 += xv * w0r[64 + jj]; s1 += xv * w1r[64 + jj]; }
      Hl[0*HBUF + r*HSTR + u] = f2bf(s0);
      Hl[1*HBUF + r*HSTR + u] = f2bf(s1);
    }
  }

  // ---- c-state in registers: ci = (p*2+mt)*4+q, 16 per layer
  float c0s[16], c1s[16];
  #pragma unroll
  for (int i = 0; i < 16; ++i) { c0s[i] = 0.f; c1s[i] = 0.f; }

  __syncthreads();

  const int arow = lane & 15, koff = (lane >> 4) * 8;

  // tile-stage helpers (slot = (kt%3)*4+g for M1/M2; s%12 for M3)
  auto issueM1 = [&](int p, int kt){
    #pragma unroll
    for (int g = 0; g < 4; ++g)
      stage16(pk0i + ((size_t)((g*16 + wv*2 + p)*NKT0 + kt))*512 + lane*8,
              RG + ((kt%3)*4 + g)*512);
  };
  auto issueM2 = [&](int p, int kt){
    #pragma unroll
    for (int g = 0; g < 4; ++g)
      stage16(pk1i + ((size_t)((g*16 + wv*2 + p)*NKT1 + kt))*512 + lane*8,
              RG + ((kt%3)*4 + g)*512);
  };

  int ia = 0, ib = 1, ic = 2;   // ia=h0(t), ib=h1(t), ic=free

  for (int t = 0; t < T; ++t) {
    const unsigned short* Ha = Hl + ia*HBUF;
    const unsigned short* Hb = Hl + ib*HBUF;
    unsigned short*       Hc = Hl + ic*HBUF;
    unsigned short*       HaW= Hl + ia*HBUF;
    unsigned short*       HIDb = Hl + ib*HBUF;   // HID overlays dead h1(t) buffer in M3/M4

    // ===== M1: gates0 (bias in X col 73); h0n -> H[ic] =====
    #pragma unroll
    for (int p = 0; p < 2; ++p) {
      LGKM0;                         // slot-reuse safety across p0->p1 (free after barrier)
      issueM1(p, 0); issueM1(p, 1);  // prologue: 2 kt-groups in flight

      f32x4 acc[2][4];
      #pragma unroll
      for (int mt = 0; mt < 2; ++mt)
        #pragma unroll
        for (int g = 0; g < 4; ++g) acc[mt][g] = (f32x4){0.f,0.f,0.f,0.f};

      #pragma unroll
      for (int kt = 0; kt < NKT0; ++kt) {
        WAITVM(kt < NKT0-1 ? 4 : 0);       // group kt staged
        short8 w[4];
        #pragma unroll
        for (int g = 0; g < 4; ++g)
          w[g] = *(const short8*)(RG + ((kt%3)*4 + g)*512 + lane*8);
        short8 a[2];
        if (kt < 3) {
          #pragma unroll
          for (int mt = 0; mt < 2; ++mt)
            a[mt] = *(const short8*)(Xl + (mt*16 + arow)*XSTR + kt*32 + koff);
        } else {
          #pragma unroll
          for (int mt = 0; mt < 2; ++mt)
            a[mt] = *(const short8*)(Ha + (mt*16 + arow)*HSTR + (kt - 3)*32 + koff);
        }
        #pragma unroll
        for (int g = 0; g < 4; ++g)
          #pragma unroll
          for (int mt = 0; mt < 2; ++mt)
            acc[mt][g] = __builtin_amdgcn_mfma_f32_16x16x32_bf16(a[mt], w[g], acc[mt][g], 0, 0, 0);
        if (kt + 2 < NKT0) { LGKM6; issueM1(p, kt+2); }   // guard: kt-1's reads retired
      }

      const int u = (wv*2 + p)*16 + (lane & 15);
      #pragma unroll
      for (int mt = 0; mt < 2; ++mt) {
        #pragma unroll
        for (int q = 0; q < 4; ++q) {
          float iv = sigm(acc[mt][0][q]);
          float fv = sigm(acc[mt][1][q]);
          float gv = ftanh(acc[mt][2][q]);
          float ov = sigm(acc[mt][3][q]);
          int ci = (p*2 + mt)*4 + q;
          float cn = fv * c0s[ci] + iv * gv;
          c0s[ci] = cn;
          float hn = ov * ftanh(cn);
          int r = mt*16 + ((lane >> 4) << 2) + q;
          Hc[r*HSTR + u] = f2bf(hn);
        }
      }
    }
    __syncthreads();  // B1 (ring drained: all M1 tiles consumed)

    // ===== M2: gates1 (bias via BT kt=16); h1n -> H[ia] =====
    #pragma unroll
    for (int p = 0; p < 2; ++p) {
      LGKM0;
      issueM2(p, 0); issueM2(p, 1);

      f32x4 acc[2][4];
      #pragma unroll
      for (int mt = 0; mt < 2; ++mt)
        #pragma unroll
        for (int g = 0; g < 4; ++g) acc[mt][g] = (f32x4){0.f,0.f,0.f,0.f};

      #pragma unroll
      for (int kt = 0; kt < NKT1; ++kt) {
        WAITVM(kt < NKT1-1 ? 4 : 0);
        short8 w[4];
        #pragma unroll
        for (int g = 0; g < 4; ++g)
          w[g] = *(const short8*)(RG + ((kt%3)*4 + g)*512 + lane*8);
        short8 a[2];
        if (kt < 8) {
          #pragma unroll
          for (int mt = 0; mt < 2; ++mt)
            a[mt] = *(const short8*)(Hc + (mt*16 + arow)*HSTR + kt*32 + koff);
        } else if (kt < 16) {
          #pragma unroll
          for (int mt = 0; mt < 2; ++mt)
            a[mt] = *(const short8*)(Hb + (mt*16 + arow)*HSTR + (kt - 8)*32 + koff);
        } else {
          #pragma unroll
          for (int mt = 0; mt < 2; ++mt)
            a[mt] = *(const short8*)(BTl + (mt*16 + arow)*BTSTR + koff);
        }
        #pragma unroll
        for (int g = 0; g < 4; ++g)
          #pragma unroll
          for (int mt = 0; mt < 2; ++mt)
            acc[mt][g] = __builtin_amdgcn_mfma_f32_16x16x32_bf16(a[mt], w[g], acc[mt][g], 0, 0, 0);
        if (kt + 2 < NKT1) { LGKM6; issueM2(p, kt+2); }
      }

      const int u = (wv*2 + p)*16 + (lane & 15);
      #pragma unroll
      for (int mt = 0; mt < 2; ++mt) {
        #pragma unroll
        for (int q = 0; q < 4; ++q) {
          float iv = sigm(acc[mt][0][q]);
          float fv = sigm(acc[mt][1][q]);
          float gv = ftanh(acc[mt][2][q]);
          float ov = sigm(acc[mt][3][q]);
          int ci = (p*2 + mt)*4 + q;
          float cn = fv * c1s[ci] + iv * gv;
          c1s[ci] = cn;
          float hn = ov * ftanh(cn);
          int r = mt*16 + ((lane >> 4) << 2) + q;
          HaW[r*HSTR + u] = f2bf(hn);
        }
      }
    }
    __syncthreads();  // B2

    // ===== M3: hid = relu(h1n @ out_w1^T + b) -> HID bf16 overlaid on H[ib] =====
    {
      #pragma unroll
      for (int s = 0; s < 8; ++s)
        stage16(pkoi + ((size_t)(wv*NKTO + s))*512 + lane*8, RG + (s%12)*512);

      f32x4 acc3[2];
      #pragma unroll
      for (int mt = 0; mt < 2; ++mt) acc3[mt] = (f32x4){0.f,0.f,0.f,0.f};

      #pragma unroll
      for (int kt = 0; kt < NKTO; ++kt) {
        WAITVM(((kt==0 ? 8 : 9) - kt) - 1);
        const short8 bw = *(const short8*)(RG + (kt%12)*512 + lane*8);
        short8 a[2];
        if (kt < 8) {
          #pragma unroll
          for (int mt = 0; mt < 2; ++mt)
            a[mt] = *(const short8*)(HaW + (mt*16 + arow)*HSTR + kt*32 + koff);
        } else {
          #pragma unroll
          for (int mt = 0; mt < 2; ++mt)
            a[mt] = *(const short8*)(BTl + (mt*16 + arow)*BTSTR + koff);
        }
        #pragma unroll
        for (int mt = 0; mt < 2; ++mt)
          acc3[mt] = __builtin_amdgcn_mfma_f32_16x16x32_bf16(a[mt], bw, acc3[mt], 0, 0, 0);
        if (kt == 0)
          stage16(pkoi + ((size_t)(wv*NKTO + 8))*512 + lane*8, RG + (8%12)*512);
      }
      const int uh = wv*16 + (lane & 15);
      #pragma unroll
      for (int mt = 0; mt < 2; ++mt)
        #pragma unroll
        for (int q = 0; q < 4; ++q) {
          float hv = fmaxf(acc3[mt][q], 0.f);
          int r = mt*16 + ((lane >> 4) << 2) + q;
          HIDb[r*HID2STR + uh] = f2bf(hv);
        }
    }
    __syncthreads();  // B3

    // ===== M4: out = hid @ out_w2^T + ob2; 16 thr/row, 8 cols, shfl width 16 =====
    {
      int r = tid >> 4, e = tid & 15;
      const unsigned short* hrow = HIDb + r*HID2STR + e*8;
      float s0 = 0.f, s1 = 0.f, s2 = 0.f;
      #pragma unroll
      for (int k = 0; k < 8; ++k) {
        float hv = bf2f(hrow[k]);
        int kk = e*8 + k;
        s0 += hv * OW2l[kk];
        s1 += hv * OW2l[128 + kk];
        s2 += hv * OW2l[256 + kk];
      }
      #pragma unroll
      for (int d = 8; d; d >>= 1) {
        s0 += __shfl_down(s0, d, 16);
        s1 += __shfl_down(s1, d, 16);
        s2 += __shfl_down(s2, d, 16);
      }
      if (e == 0) {
        s0 += OB2l[0]; s1 += OB2l[1]; s2 += OB2l[2];
        int gr = row0 + r;
        float* orow = out + (size_t)gr * (T*3) + t*3;
        orow[0] = s0; orow[1] = s1; orow[2] = s2;
        Xl[r*XSTR + 0] = f2bf(s0);
        Xl[r*XSTR + 1] = f2bf(s1);
        Xl[r*XSTR + 2] = f2bf(s2);
      }
    }
    __syncthreads();  // B4 (drains out-stores too -> clean vmcnt for next step)

    int tmp = ia; ia = ic; ic = ib; ib = tmp;
  }
}

extern "C" void kernel_launch(void* const* d_in, const int* in_sizes, int n_in,
                              void* d_out, int out_size, void* d_ws, size_t ws_size,
                              hipStream_t stream){
  const float* z    = (const float*)d_in[0];
  const float* cond = (const float*)d_in[1];
  const float* fiw  = (const float*)d_in[2];
  const float* fib  = (const float*)d_in[3];
  const float* wih0 = (const float*)d_in[4];
  const float* whh0 = (const float*)d_in[5];
  const float* bih0 = (const float*)d_in[6];
  const float* bhh0 = (const float*)d_in[7];
  const float* wih1 = (const float*)d_in[8];
  const float* whh1 = (const float*)d_in[9];
  const float* bih1 = (const float*)d_in[10];
  const float* bhh1 = (const float*)d_in[11];
  const float* ow1  = (const float*)d_in[12];
  const float* ob1  = (const float*)d_in[13];
  const float* ow2  = (const float*)d_in[14];
  const float* ob2  = (const float*)d_in[15];
  const int*   seqp = (const int*)d_in[16];
  unsigned short* wsb = (unsigned short*)d_ws;
  float* outp = (float*)d_out;

  hipFuncSetAttribute((const void*)traj_main,
                      hipFuncAttributeMaxDynamicSharedMemorySize, LDS_TOTAL);

  int packtot = PK0_ELEMS + PK1_ELEMS + PKO_ELEMS;
  pack_weights<<<(packtot + 255)/256, 256, 0, stream>>>(wih0, whh0, bih0, bhh0,
                                                        wih1, whh1, bih1, bhh1,
                                                        ow1, ob1, wsb);
  traj_main<<<16384/BROWS, NTHR, LDS_TOTAL, stream>>>(z, cond, fiw, fib,
                                                      ow2, ob2, wsb, seqp, outp);
}

// Round 13
// 5721.482 us; speedup vs baseline: 3.5220x; 1.5854x over previous
//
#include <hip/hip_runtime.h>
#include <hip/hip_bf16.h>

typedef short short8 __attribute__((ext_vector_type(8)));
typedef float f32x4 __attribute__((ext_vector_type(4)));

#define BROWS 64
#define NTHR  512
#define XK    96
#define XSTR  104
#define HSTR  264
#define HIDSTR 129
#define NKT0  11
#define NKT1  16
#define NKTO  8
#define PK0_ELEMS (64*NKT0*512)
#define PK1_ELEMS (64*NKT1*512)
#define PKO_ELEMS (8*NKTO*512)

// LDS layout (bytes) — 149,264 B, STATIC (compile-time visible)
#define L_X    0
#define L_H    13312
#define HBUF   (BROWS*HSTR)          // ushort elems per H buffer (3 rotating buffers)
#define HBUF_B (HBUF*2)              // 33792 bytes
#define L_HID  (L_H + 3*HBUF_B)      // 114688 : [64][129] f32
#define L_OW2  (L_HID + BROWS*HIDSTR*4) // 147712
#define L_OB2  (L_OW2 + 1536)        // 149248
#define LDS_TOTAL 149264

__device__ inline unsigned short f2bf(float x){
  unsigned u = __float_as_uint(x);
  u += 0x7FFFu + ((u >> 16) & 1u);
  return (unsigned short)(u >> 16);
}
__device__ inline float bf2f(unsigned short s){ return __uint_as_float(((unsigned)s) << 16); }
__device__ inline float sigm(float x){ return 1.f / (1.f + __expf(-x)); }
__device__ inline float ftanh(float x){ float e = __expf(2.f*x); return 1.f - 2.f/(e + 1.f); }

// ---------------- weight pre-pack: fp32 -> single bf16, MFMA B-fragment lane order ----
// layout (ushort): region base + ((ntG*NKT + kt)*64 + lane)*8 + j
// B-frag (16x16x32): lane l holds B[k=(l>>4)*8+j][n=l&15], j=0..7
// Layer-0 K-space: [0..2]=cur, [3..66]=z, [67..72]=cond, [73]=BIAS (X col 73 == 1.0),
//                  [74..95]=pad0, [96..351]=w_hh0
__global__ void pack_weights(const float* __restrict__ wih0, const float* __restrict__ whh0,
                             const float* __restrict__ bih0, const float* __restrict__ bhh0,
                             const float* __restrict__ wih1, const float* __restrict__ whh1,
                             const float* __restrict__ ow1,
                             unsigned short* __restrict__ wsb){
  int idx = blockIdx.x * blockDim.x + threadIdx.x;
  int total = PK0_ELEMS + PK1_ELEMS + PKO_ELEMS;
  if (idx >= total) return;
  float w;
  size_t off;
  if (idx < PK0_ELEMS) {
    int nt = idx / (NKT0*512), rem = idx % (NKT0*512), kt = rem / 512, li = rem % 512;
    int lane = li >> 3, j = li & 7;
    int n = lane & 15, k = ((lane >> 4) << 3) + j;
    int Kg = kt*32 + k, g = nt*16 + n;          // g = global gate-unit index [0,1024)
    if (Kg < 73)        w = wih0[g*73 + Kg];
    else if (Kg == 73)  w = bih0[g] + bhh0[g];  // bias via constant-1 input column
    else if (Kg < XK)   w = 0.f;
    else                w = whh0[g*256 + (Kg - XK)];
    off = ((size_t)(nt*NKT0 + kt)*64 + lane)*8 + j;
  } else if (idx < PK0_ELEMS + PK1_ELEMS) {
    int i2 = idx - PK0_ELEMS;
    int nt = i2 / (NKT1*512), rem = i2 % (NKT1*512), kt = rem / 512, li = rem % 512;
    int lane = li >> 3, j = li & 7;
    int n = lane & 15, k = ((lane >> 4) << 3) + j;
    int Kg = kt*32 + k, g = nt*16 + n;
    w = (Kg < 256) ? wih1[g*256 + Kg] : whh1[g*256 + (Kg - 256)];
    off = (size_t)PK0_ELEMS + ((size_t)(nt*NKT1 + kt)*64 + lane)*8 + j;
  } else {
    int i2 = idx - PK0_ELEMS - PK1_ELEMS;
    int nt = i2 / (NKTO*512), rem = i2 % (NKTO*512), kt = rem / 512, li = rem % 512;
    int lane = li >> 3, j = li & 7;
    int n = lane & 15, k = ((lane >> 4) << 3) + j;
    int Kg = kt*32 + k, uh = nt*16 + n;
    w = ow1[uh*256 + Kg];
    off = (size_t)PK0_ELEMS + (size_t)PK1_ELEMS + ((size_t)(nt*NKTO + kt)*64 + lane)*8 + j;
  }
  wsb[off] = f2bf(w);
}

// ---------------- persistent rollout kernel ----------------
// R1-R12 diagnosis: with DYNAMIC LDS the compiler cannot see that only 1 block/CU
// fits, assumes 2 workgroups/CU, and budgets VGPR = 65536/NTHR (512thr -> 128).
// Live demand (acc 64 + c-state 64 + ring + frags ~ 210) then spills every step,
// polluting L2 and making weight loads miss. Fix: STATIC __shared__ (149KB,
// compile-time visible -> provably 1 block/CU -> 2 waves/SIMD -> 256-reg budget)
// plus amdgpu_num_vgpr(256) to set the allocator budget directly.
__global__ void __launch_bounds__(NTHR)
__attribute__((amdgpu_num_vgpr(256)))
traj_main(const float* __restrict__ z, const float* __restrict__ cond,
          const float* __restrict__ fiw, const float* __restrict__ fib,
          const float* __restrict__ bih1, const float* __restrict__ bhh1,
          const float* __restrict__ ob1,  const float* __restrict__ ow2,
          const float* __restrict__ ob2,
          const unsigned short* __restrict__ wsb, const int* __restrict__ seqp,
          float* __restrict__ out){
  __shared__ __align__(16) char smem[LDS_TOTAL];
  unsigned short* Xl  = (unsigned short*)(smem + L_X);    // [64][104] bf16: cur|z|cond|1|pad
  unsigned short* Hl  = (unsigned short*)(smem + L_H);    // 3 x [64][264] bf16 rotating
  float*          HIDl= (float*)(smem + L_HID);           // [64][129] f32
  float*          OW2l= (float*)(smem + L_OW2);           // [3][128]
  float*          OB2l= (float*)(smem + L_OB2);           // [3]

  const int tid = threadIdx.x, wv = tid >> 6, lane = tid & 63;
  const int bid = blockIdx.x;
  const int row0 = bid * BROWS;
  const int T = *seqp;

  const unsigned short* pk0i = wsb;
  const unsigned short* pk1i = wsb + (size_t)PK0_ELEMS;
  const unsigned short* pkoi = wsb + (size_t)PK0_ELEMS + (size_t)PK1_ELEMS;

  // ---- init: fill X (cur0 = cond[:3], z, cond, 1.0 bias col), copy ow2/ob2 to LDS
  {
    int r = tid >> 3, seg = tid & 7;
    int gr = row0 + r;
    for (int c = seg*13; c < seg*13 + 13; ++c) {
      float v;
      if (c < 3)        v = cond[gr*6 + c];
      else if (c < 67)  v = z[gr*64 + (c - 3)];
      else if (c < 73)  v = cond[gr*6 + (c - 67)];
      else if (c == 73) v = 1.0f;               // bias multiplier column
      else              v = 0.f;
      Xl[r*XSTR + c] = f2bf(v);
    }
  }
  if (tid < 384) OW2l[tid] = ow2[tid];
  if (tid < 3)   OB2l[tid] = ob2[tid];

  // ---- init h0 -> H[0], h1 -> H[1]  (fp32 VALU, one-time)
  {
    int r = tid >> 3, ub = (tid & 7) * 32;
    int gr = row0 + r;
    #pragma unroll 1
    for (int u = ub; u < ub + 32; ++u) {
      float s0 = fib[u], s1 = fib[256 + u];
      const float* w0r = fiw + (size_t)u * 70;
      const float* w1r = fiw + (size_t)(256 + u) * 70;
      for (int jj = 0; jj < 64; ++jj) { float xv = z[gr*64 + jj]; s0 += xv * w0r[jj]; s1 += xv * w1r[jj]; }
      for (int jj = 0; jj < 6;  ++jj) { float xv = cond[gr*6 + jj]; s0 += xv * w0r[64 + jj]; s1 += xv * w1r[64 + jj]; }
      Hl[0*HBUF + r*HSTR + u] = f2bf(s0);
      Hl[1*HBUF + r*HSTR + u] = f2bf(s1);
    }
  }

  // ---- per-lane layer-1 bias preload (layer-0 bias folded into weights)
  float bias1r[8];
  #pragma unroll
  for (int p = 0; p < 2; ++p) {
    int u = wv*32 + p*16 + (lane & 15);
    #pragma unroll
    for (int g = 0; g < 4; ++g)
      bias1r[p*4 + g] = bih1[g*256 + u] + bhh1[g*256 + u];
  }
  float ob1r = ob1[wv*16 + (lane & 15)];

  // ---- c-state in registers (fixed (row,unit)->lane mapping from MFMA C layout)
  float c0s[32], c1s[32];
  #pragma unroll
  for (int i = 0; i < 32; ++i) { c0s[i] = 0.f; c1s[i] = 0.f; }

  __syncthreads();

  const int arow = lane & 15, koff = (lane >> 4) * 8;

  // rotating buffer roles: ia = h0(t), ib = h1(t), ic = free
  int ia = 0, ib = 1, ic = 2;

  for (int t = 0; t < T; ++t) {
    const unsigned short* Ha = Hl + ia*HBUF;  // h0(t)
    const unsigned short* Hb = Hl + ib*HBUF;  // h1(t)
    unsigned short*       Hc = Hl + ic*HBUF;  // free -> h0(t+1)
    unsigned short*       HaW= Hl + ia*HBUF;  // retired after B1 -> h1(t+1)

    // ===== M1: gates0 = [x|1|h0] @ W0^T (bias in col 73), cell 0; h0n -> H[ic] =====
    #pragma unroll
    for (int p = 0; p < 2; ++p) {
      const unsigned short* wb = pk0i + ((size_t)((wv*2 + p)*NKT0)*64 + lane)*8;

      // depth-1 prefetch ring (double buffer)
      short8 wh[2][4];
      #pragma unroll
      for (int g = 0; g < 4; ++g)
        wh[0][g] = *(const short8*)(wb + (size_t)g*(16*NKT0*512));

      f32x4 acc[4][4];
      #pragma unroll
      for (int mt = 0; mt < 4; ++mt)
        #pragma unroll
        for (int g = 0; g < 4; ++g) acc[mt][g] = (f32x4){0.f, 0.f, 0.f, 0.f};

      #pragma unroll
      for (int kt = 0; kt < NKT0; ++kt) {
        const int cb = kt & 1, nb = cb ^ 1;
        if (kt + 1 < NKT0) {
          #pragma unroll
          for (int g = 0; g < 4; ++g)
            wh[nb][g] = *(const short8*)(wb + (size_t)g*(16*NKT0*512) + (size_t)(kt+1)*512);
        }
        short8 a[4];
        if (kt < 3) {
          #pragma unroll
          for (int mt = 0; mt < 4; ++mt)
            a[mt] = *(const short8*)(Xl + (mt*16 + arow)*XSTR + kt*32 + koff);
        } else {
          #pragma unroll
          for (int mt = 0; mt < 4; ++mt)
            a[mt] = *(const short8*)(Ha + (mt*16 + arow)*HSTR + (kt - 3)*32 + koff);
        }
        #pragma unroll
        for (int g = 0; g < 4; ++g)
          #pragma unroll
          for (int mt = 0; mt < 4; ++mt)
            acc[mt][g] = __builtin_amdgcn_mfma_f32_16x16x32_bf16(a[mt], wh[cb][g], acc[mt][g], 0, 0, 0);
      }

      const int u = wv*32 + p*16 + (lane & 15);
      #pragma unroll
      for (int mt = 0; mt < 4; ++mt) {
        #pragma unroll
        for (int q = 0; q < 4; ++q) {
          float iv = sigm(acc[mt][0][q]);
          float fv = sigm(acc[mt][1][q]);
          float gv = ftanh(acc[mt][2][q]);
          float ov = sigm(acc[mt][3][q]);
          float cn = fv * c0s[(p*4 + mt)*4 + q] + iv * gv;
          c0s[(p*4 + mt)*4 + q] = cn;
          float hn = ov * ftanh(cn);
          int r = mt*16 + ((lane >> 4) << 2) + q;
          Hc[r*HSTR + u] = f2bf(hn);
        }
      }
    }
    __syncthreads();  // B1: h0n complete (H[ic]); H[ia] now dead

    // ===== M2: gates1 = [h0n|h1] @ W1^T (+b), cell 1; h1n -> H[ia] (retired) =====
    #pragma unroll
    for (int p = 0; p < 2; ++p) {
      const unsigned short* wb = pk1i + ((size_t)((wv*2 + p)*NKT1)*64 + lane)*8;

      short8 wh[2][4];
      #pragma unroll
      for (int g = 0; g < 4; ++g)
        wh[0][g] = *(const short8*)(wb + (size_t)g*(16*NKT1*512));

      f32x4 acc[4][4];
      #pragma unroll
      for (int mt = 0; mt < 4; ++mt)
        #pragma unroll
        for (int g = 0; g < 4; ++g) {
          float b = bias1r[p*4 + g];
          acc[mt][g] = (f32x4){b, b, b, b};
        }

      #pragma unroll
      for (int kt = 0; kt < NKT1; ++kt) {
        const int cb = kt & 1, nb = cb ^ 1;
        if (kt + 1 < NKT1) {
          #pragma unroll
          for (int g = 0; g < 4; ++g)
            wh[nb][g] = *(const short8*)(wb + (size_t)g*(16*NKT1*512) + (size_t)(kt+1)*512);
        }
        short8 a[4];
        if (kt < 8) {
          #pragma unroll
          for (int mt = 0; mt < 4; ++mt)
            a[mt] = *(const short8*)(Hc + (mt*16 + arow)*HSTR + kt*32 + koff);
        } else {
          #pragma unroll
          for (int mt = 0; mt < 4; ++mt)
            a[mt] = *(const short8*)(Hb + (mt*16 + arow)*HSTR + (kt - 8)*32 + koff);
        }
        #pragma unroll
        for (int g = 0; g < 4; ++g)
          #pragma unroll
          for (int mt = 0; mt < 4; ++mt)
            acc[mt][g] = __builtin_amdgcn_mfma_f32_16x16x32_bf16(a[mt], wh[cb][g], acc[mt][g], 0, 0, 0);
      }

      const int u = wv*32 + p*16 + (lane & 15);
      #pragma unroll
      for (int mt = 0; mt < 4; ++mt) {
        #pragma unroll
        for (int q = 0; q < 4; ++q) {
          float iv = sigm(acc[mt][0][q]);
          float fv = sigm(acc[mt][1][q]);
          float gv = ftanh(acc[mt][2][q]);
          float ov = sigm(acc[mt][3][q]);
          float cn = fv * c1s[(p*4 + mt)*4 + q] + iv * gv;
          c1s[(p*4 + mt)*4 + q] = cn;
          float hn = ov * ftanh(cn);
          int r = mt*16 + ((lane >> 4) << 2) + q;
          HaW[r*HSTR + u] = f2bf(hn);   // retired h0(t) buffer: safe, no wave reads H[ia] now
        }
      }
    }
    __syncthreads();  // B2: h1n visible in H[ia]

    // ===== M3: hid = relu(h1n @ out_w1^T + out_b1) -> LDS fp32 (1 unit-tile per wave) =====
    {
      const unsigned short* wb = pkoi + ((size_t)(wv*NKTO)*64 + lane)*8;
      short8 wh[2];
      wh[0] = *(const short8*)(wb);

      f32x4 acc3[4];
      #pragma unroll
      for (int mt = 0; mt < 4; ++mt) acc3[mt] = (f32x4){ob1r, ob1r, ob1r, ob1r};

      #pragma unroll
      for (int kt = 0; kt < NKTO; ++kt) {
        const int cb = kt & 1, nb = cb ^ 1;
        if (kt + 1 < NKTO)
          wh[nb] = *(const short8*)(wb + (size_t)(kt+1)*512);
        short8 a[4];
        #pragma unroll
        for (int mt = 0; mt < 4; ++mt)
          a[mt] = *(const short8*)(HaW + (mt*16 + arow)*HSTR + kt*32 + koff);
        #pragma unroll
        for (int mt = 0; mt < 4; ++mt)
          acc3[mt] = __builtin_amdgcn_mfma_f32_16x16x32_bf16(a[mt], wh[cb], acc3[mt], 0, 0, 0);
      }
      const int uh = wv*16 + (lane & 15);
      #pragma unroll
      for (int mt = 0; mt < 4; ++mt)
        #pragma unroll
        for (int q = 0; q < 4; ++q) {
          float hv = fmaxf(acc3[mt][q], 0.f);
          int r = mt*16 + ((lane >> 4) << 2) + q;
          HIDl[r*HIDSTR + uh] = hv;
        }
    }
    __syncthreads();  // B3: hid visible

    // ===== M4: out = hid @ out_w2^T + out_b2, all 512 threads:
    // 8 threads per row, 16-wide k-partials, shfl-reduce width 8 =====
    {
      int r = tid >> 3, e = tid & 7;
      const float* hrow = HIDl + r*HIDSTR + e*16;
      float s0 = 0.f, s1 = 0.f, s2 = 0.f;
      #pragma unroll
      for (int k = 0; k < 16; ++k) {
        float hv = hrow[k];
        int kk = e*16 + k;
        s0 += hv * OW2l[kk];
        s1 += hv * OW2l[128 + kk];
        s2 += hv * OW2l[256 + kk];
      }
      #pragma unroll
      for (int d = 4; d; d >>= 1) {
        s0 += __shfl_down(s0, d, 8);
        s1 += __shfl_down(s1, d, 8);
        s2 += __shfl_down(s2, d, 8);
      }
      if (e == 0) {
        s0 += OB2l[0]; s1 += OB2l[1]; s2 += OB2l[2];
        int gr = row0 + r;
        float* orow = out + (size_t)gr * (T*3) + t*3;
        orow[0] = s0; orow[1] = s1; orow[2] = s2;
        Xl[r*XSTR + 0] = f2bf(s0);
        Xl[r*XSTR + 1] = f2bf(s1);
        Xl[r*XSTR + 2] = f2bf(s2);
      }
    }
    __syncthreads();  // B4: cur visible, hid reads done

    // rotate roles: h0(t+1) in old ic; h1(t+1) in old ia; old ib freed
    int tmp = ia; ia = ic; ic = ib; ib = tmp;
  }
}

extern "C" void kernel_launch(void* const* d_in, const int* in_sizes, int n_in,
                              void* d_out, int out_size, void* d_ws, size_t ws_size,
                              hipStream_t stream){
  const float* z    = (const float*)d_in[0];
  const float* cond = (const float*)d_in[1];
  const float* fiw  = (const float*)d_in[2];
  const float* fib  = (const float*)d_in[3];
  const float* wih0 = (const float*)d_in[4];
  const float* whh0 = (const float*)d_in[5];
  const float* bih0 = (const float*)d_in[6];
  const float* bhh0 = (const float*)d_in[7];
  const float* wih1 = (const float*)d_in[8];
  const float* whh1 = (const float*)d_in[9];
  const float* bih1 = (const float*)d_in[10];
  const float* bhh1 = (const float*)d_in[11];
  const float* ow1  = (const float*)d_in[12];
  const float* ob1  = (const float*)d_in[13];
  const float* ow2  = (const float*)d_in[14];
  const float* ob2  = (const float*)d_in[15];
  const int*   seqp = (const int*)d_in[16];
  unsigned short* wsb = (unsigned short*)d_ws;
  float* outp = (float*)d_out;

  int packtot = PK0_ELEMS + PK1_ELEMS + PKO_ELEMS;
  pack_weights<<<(packtot + 255)/256, 256, 0, stream>>>(wih0, whh0, bih0, bhh0,
                                                        wih1, whh1, ow1, wsb);
  traj_main<<<16384/BROWS, NTHR, 0, stream>>>(z, cond, fiw, fib,
                                              bih1, bhh1,
                                              ob1, ow2, ob2, wsb, seqp, outp);
}